// Round 1
// 1417.191 us; speedup vs baseline: 1.1251x; 1.1251x over previous
//
#include <hip/hip_runtime.h>
#include <cstdint>

#define N_U 100000
#define N_I 50000
#define DIM 64
#define RANK 5
#define NNZ_ 2000000
#define M_U 2048
#define M_I 4096
#define NSEG 150000   // N_U + N_I combined segment count
#define BSH 6         // bucket = seg >> 6  (64 segments per bucket)
#define NBUCK 2344    // ceil(NSEG/64)
#define NPB 512       // place blocks
#define CH 3907       // edges per place block (ceil(NNZ_/NPB))

// neg-GEMM tiling
#define CPC 3136
#define NCH_U 32
#define NCH_I 16
#define NPAD_U (CPC * NCH_U)
#define NPAD_I (CPC * NCH_I)

typedef __attribute__((ext_vector_type(8))) short short8;
typedef __attribute__((ext_vector_type(4))) float floatx4;

// ---- workspace layout (float offsets) ----
static constexpr size_t ZU1 = 0;                       // 6.4M
static constexpr size_t ZI1 = 6400000;                 // 3.2M
static constexpr size_t EDGE = 9600000;                // 4M float2 = 8M floats
static constexpr size_t P_OFF = 17600000;              // 320
static constexpr size_t Q_OFF = 17600320;              // 320
static constexpr size_t ACC_OFF = 17600640;            // 1 (pad to 704)
static constexpr size_t CNT_OFF = 17600704;            // 150000 ints
static constexpr size_t OFF_OFF = 17750704;            // 150016 ints
static constexpr size_t BCNT_OFF = 17900720;           // NBUCK ints (<=9375 region)
static constexpr size_t BOFF_OFF = 17910144;           // NBUCK ints
static constexpr size_t BSUM_OFF = 17919552;           // 1024 ints
static constexpr size_t EU0 = 17920576;                // 6.4M
static constexpr size_t EI0 = EU0 + 6400000;           // 3.2M
static constexpr size_t PART_U = EI0 + 3200000;        // 2048*32
static constexpr size_t PART_I = PART_U + (size_t)M_U * NCH_U;  // 4096*16
// end = PART_I + M_I*NCH_I = 27,651,648 floats = 110.6 MB (< 115.7 MB proven in R1)
// ---- staging overlays, live ONLY during CSR build (before spmm / before place2) ----
static constexpr size_t STAGE_SV = 0;                  // 4M float2 over ZU1+ZI1
static constexpr size_t BH_OFF = EDGE;                 // NPB*NBUCK ints, dead before place2
static constexpr size_t BHP_OFF = EDGE + (size_t)NPB * NBUCK;  // NPB*NBUCK ints
// BH+BHP = 2*512*2344 = 2,400,256 floats < 8M edge region ✓
// ---- bf16 overlay inside ZU1 (zu1/zi1 dead after layer-2 spmm) ----
static constexpr size_t EBU16 = 0;                     // 3,211,264 fl
static constexpr size_t EBI16 = 3211264;               // 1,605,632 fl
static constexpr size_t GBU16 = EBI16 + 1605632;       // 65,536 fl
static constexpr size_t GBI16 = GBU16 + 65536;         // 131,072 fl -> end 5,013,504 < 6.4M

static __device__ __forceinline__ short f2bf(float x) {
    unsigned u = __builtin_bit_cast(unsigned, x);
    unsigned r = (u + 0x7fffu + ((u >> 16) & 1u)) >> 16;
    return (short)r;
}

__global__ void ew_add_kernel(const float4* __restrict__ a, const float4* __restrict__ b,
                              float4* __restrict__ o, int n) {
    int i = blockIdx.x * blockDim.x + threadIdx.x;
    if (i < n) {
        float4 x = a[i], y = b[i];
        o[i] = make_float4(x.x + y.x, x.y + y.y, x.z + y.z, x.w + y.w);
    }
}

// ---------- atomic-free CSR/CSC build ----------
// phase 1: per-block LDS bucket histogram, dense writeout bh[block][bucket]
__global__ __launch_bounds__(256) void bhist_kernel(const int* __restrict__ rows,
                                                    const int* __restrict__ cols,
                                                    int* __restrict__ bh) {
    __shared__ int h[NBUCK];
    for (int i = threadIdx.x; i < NBUCK; i += 256) h[i] = 0;
    __syncthreads();
    int b = blockIdx.x;
    int lo = b * CH, hi = min(lo + CH, NNZ_);
    for (int e = lo + threadIdx.x; e < hi; e += 256) {
        atomicAdd(&h[rows[e] >> BSH], 1);
        atomicAdd(&h[(N_U + cols[e]) >> BSH], 1);
    }
    __syncthreads();
    for (int i = threadIdx.x; i < NBUCK; i += 256) bh[(size_t)b * NBUCK + i] = h[i];
}

// phase 2: coalesced column scan: one thread per bucket, serial over NPB blocks.
// bhp[b][j] = exclusive prefix over blocks, bcnt[j] = total.
__global__ __launch_bounds__(256) void col_scan_kernel(const int* __restrict__ bh,
                                                       int* __restrict__ bhp,
                                                       int* __restrict__ bcnt) {
    int j = blockIdx.x * 256 + threadIdx.x;
    if (j >= NBUCK) return;
    int run = 0;
#pragma unroll 8
    for (int b = 0; b < NPB; b++) {
        int v = bh[(size_t)b * NBUCK + j];
        bhp[(size_t)b * NBUCK + j] = run;
        run += v;
    }
    bcnt[j] = run;
}

__global__ void scan1_kernel(const int* __restrict__ cnt, int* __restrict__ bsum, int n) {
    int i = blockIdx.x * 256 + threadIdx.x;
    int v = (i < n) ? cnt[i] : 0;
#pragma unroll
    for (int off = 32; off; off >>= 1) v += __shfl_down(v, off);
    __shared__ int ls[4];
    int lane = threadIdx.x & 63, w = threadIdx.x >> 6;
    if (lane == 0) ls[w] = v;
    __syncthreads();
    if (threadIdx.x == 0) bsum[blockIdx.x] = ls[0] + ls[1] + ls[2] + ls[3];
}

__global__ void scan2_kernel(int* __restrict__ bsum, int nb) {
    __shared__ int s[1024];
    int t = threadIdx.x;
    s[t] = (t < nb) ? bsum[t] : 0;
    __syncthreads();
    for (int off = 1; off < 1024; off <<= 1) {
        int v = (t >= off) ? s[t - off] : 0;
        __syncthreads();
        s[t] += v;
        __syncthreads();
    }
    if (t < nb) bsum[t] = (t == 0) ? 0 : s[t - 1];
}

__global__ void scan3_kernel(const int* __restrict__ cnt, const int* __restrict__ bsum,
                             int* __restrict__ off, int n) {
    __shared__ int s[256];
    int i = blockIdx.x * 256 + threadIdx.x;
    int t = threadIdx.x;
    int c = (i < n) ? cnt[i] : 0;
    s[t] = c;
    __syncthreads();
    for (int o = 1; o < 256; o <<= 1) {
        int v = (t >= o) ? s[t - o] : 0;
        __syncthreads();
        s[t] += v;
        __syncthreads();
    }
    if (i < n) off[i] = bsum[blockIdx.x] + s[t] - c;
}

// phase 3: deterministic placement into bucket-grouped staging (no global atomics).
// entry = (idx | (seg&63)<<20, val) -- idx < 2^20, 6-bit nibble recovers segment in place2.
__global__ __launch_bounds__(256) void bucket_place_kernel(
    const int* __restrict__ rows, const int* __restrict__ cols, const float* __restrict__ vals,
    const int* __restrict__ boff, const int* __restrict__ bhp, float2* __restrict__ sv) {
    __shared__ int h[NBUCK];
    for (int i = threadIdx.x; i < NBUCK; i += 256) h[i] = 0;
    __syncthreads();
    int b = blockIdx.x;
    int lo = b * CH, hi = min(lo + CH, NNZ_);
    const int* bhpb = bhp + (size_t)b * NBUCK;
    for (int e = lo + threadIdx.x; e < hi; e += 256) {
        int r = rows[e], c = cols[e];
        float v = vals[e];
        int bu = r >> BSH;
        int ru = atomicAdd(&h[bu], 1);
        sv[boff[bu] + bhpb[bu] + ru] = make_float2(__int_as_float(c | ((r & 63) << 20)), v);
        int sI = N_U + c;
        int bi = sI >> BSH;
        int ri = atomicAdd(&h[bi], 1);
        sv[boff[bi] + bhpb[bi] + ri] = make_float2(__int_as_float(r | ((sI & 63) << 20)), v);
    }
}

// phase 4: one block per bucket: exact CSR placement of its entries,
// emit per-segment cnt and end-offsets (random writes confined to the bucket window)
__global__ __launch_bounds__(256) void place2_kernel(const float2* __restrict__ sv,
                                                     const int* __restrict__ boff,
                                                     const int* __restrict__ bcnt,
                                                     int* __restrict__ off, int* __restrict__ cnt,
                                                     float2* __restrict__ edge) {
    int b = blockIdx.x;
    int start = boff[b], n = bcnt[b];
    __shared__ int h[64], hs[64], hc[64];
    if (threadIdx.x < 64) { h[threadIdx.x] = 0; hc[threadIdx.x] = 0; }
    __syncthreads();
    for (int i = start + threadIdx.x; i < start + n; i += 256) {
        int packed = __float_as_int(sv[i].x);
        atomicAdd(&h[(packed >> 20) & 63], 1);
    }
    __syncthreads();
    if (threadIdx.x == 0) {
        int run = 0;
#pragma unroll
        for (int k = 0; k < 64; k++) { hs[k] = run; run += h[k]; }
    }
    __syncthreads();
    if (threadIdx.x < 64) {
        int seg = b * 64 + threadIdx.x;
        if (seg < NSEG) {
            cnt[seg] = h[threadIdx.x];
            off[seg] = start + hs[threadIdx.x] + h[threadIdx.x];  // END offsets (spmm convention)
        }
    }
    for (int i = start + threadIdx.x; i < start + n; i += 256) {
        float2 p = sv[i];
        int packed = __float_as_int(p.x);
        int s = (packed >> 20) & 63;
        int r = atomicAdd(&hc[s], 1);
        edge[start + hs[s] + r] = make_float2(__int_as_float(packed & 0xFFFFF), p.y);
    }
}

// wave-per-row CSR SpMM; off[] holds END offsets, range = [end-cnt, end)
__global__ __launch_bounds__(256) void spmm_csr_kernel(
    const float2* __restrict__ edge, const int* __restrict__ off, const int* __restrict__ cnt,
    int base, const float* __restrict__ Esrc, float* __restrict__ out, float scale, int accum,
    int nrows) {
    int lane = threadIdx.x & 63;
    int row = (blockIdx.x * blockDim.x + threadIdx.x) >> 6;
    if (row >= nrows) return;
    int end = off[base + row];
    int n = cnt[base + row];
    int e = end - n;
    float acc = 0.f;
    for (; e + 4 <= end; e += 4) {
        float2 p0 = edge[e], p1 = edge[e + 1], p2 = edge[e + 2], p3 = edge[e + 3];
        float g0 = Esrc[(size_t)__float_as_int(p0.x) * 64 + lane];
        float g1 = Esrc[(size_t)__float_as_int(p1.x) * 64 + lane];
        float g2 = Esrc[(size_t)__float_as_int(p2.x) * 64 + lane];
        float g3 = Esrc[(size_t)__float_as_int(p3.x) * 64 + lane];
        acc = __builtin_fmaf(p0.y, g0, acc);
        acc = __builtin_fmaf(p1.y, g1, acc);
        acc = __builtin_fmaf(p2.y, g2, acc);
        acc = __builtin_fmaf(p3.y, g3, acc);
    }
    for (; e < end; e++) {
        float2 p = edge[e];
        acc = __builtin_fmaf(p.y, Esrc[(size_t)__float_as_int(p.x) * 64 + lane], acc);
    }
    size_t o = (size_t)row * 64 + lane;
    if (accum) out[o] += scale * acc;
    else out[o] = acc;
}

__global__ void rank_kernel(const float* __restrict__ X, const float* __restrict__ W,
                            float* __restrict__ P, int n) {
    int lane = threadIdx.x & 63;
    int wave = (blockIdx.x * blockDim.x + threadIdx.x) >> 6;
    int nw = (gridDim.x * blockDim.x) >> 6;
    float acc[RANK] = {0.f, 0.f, 0.f, 0.f, 0.f};
    for (int i = wave; i < n; i += nw) {
        float x = X[i * 64 + lane];
#pragma unroll
        for (int r = 0; r < RANK; r++) acc[r] = __builtin_fmaf(W[r * n + i], x, acc[r]);
    }
#pragma unroll
    for (int r = 0; r < RANK; r++) atomicAdd(&P[r * 64 + lane], acc[r]);
}

__global__ void pre_out_kernel(const float4* __restrict__ a, const float4* __restrict__ b,
                               float4* __restrict__ o, int n) {
    int i = blockIdx.x * blockDim.x + threadIdx.x;
    if (i < n) {
        float4 x = a[i], y = b[i];
        const float s = 1.f / 3.f;
        o[i] = make_float4((x.x + y.x) * s, (x.y + y.y) * s, (x.z + y.z) * s, (x.w + y.w) * s);
    }
}

__global__ void conv_bf16_kernel(const float* __restrict__ E, short* __restrict__ B, int n64,
                                 int npad64) {
    int i = blockIdx.x * blockDim.x + threadIdx.x;
    if (i < npad64) B[i] = (i < n64) ? f2bf(E[i]) : (short)0;
}

__global__ void gather_kernel(const int* __restrict__ ids, int m, const float* __restrict__ E0,
                              const float* __restrict__ PQ, const float* __restrict__ mulS,
                              const float* __restrict__ Eout, short* __restrict__ Gb,
                              float* __restrict__ acc, float coef) {
    int lane = threadIdx.x & 63;
    int k = (blockIdx.x * blockDim.x + threadIdx.x) >> 6;
    if (k >= m) return;
    int u = ids[k];
    float g = E0[u * 64 + lane];
#pragma unroll
    for (int r = 0; r < RANK; r++) g = __builtin_fmaf(mulS[u * RANK + r], PQ[r * 64 + lane], g);
    g *= (1.f / 3.f);
    Gb[k * 64 + lane] = f2bf(g);
    float d = g * Eout[u * 64 + lane];
#pragma unroll
    for (int off = 32; off; off >>= 1) d += __shfl_down(d, off);
    if (lane == 0) {
        float t = fminf(fmaxf(d * 5.f, -5.f), 5.f);
        atomicAdd(acc, coef * t);
    }
}

__global__ __launch_bounds__(256) void neg_mfma_kernel(const short* __restrict__ G16,
                                                       const short* __restrict__ E16,
                                                       float* __restrict__ part, int nchunk) {
    int lane = threadIdx.x & 63;
    int wave = threadIdx.x >> 6;
    int quad = lane >> 4;
    int rr = lane & 15;
    int rowbase = blockIdx.x * 64 + wave * 16;
    const short8* ga = (const short8*)(G16 + (size_t)(rowbase + rr) * 64 + quad * 8);
    short8 a0 = ga[0];
    short8 a1 = ga[4];
    int c0 = blockIdx.y * CPC;
    float s0 = 0.f, s1 = 0.f, s2 = 0.f, s3 = 0.f;
    for (int ct = 0; ct < CPC; ct += 16) {
        const short8* eb = (const short8*)(E16 + (size_t)(c0 + ct + rr) * 64 + quad * 8);
        short8 b0 = eb[0];
        short8 b1 = eb[4];
        floatx4 acc = {0.f, 0.f, 0.f, 0.f};
        acc = __builtin_amdgcn_mfma_f32_16x16x32_bf16(a0, b0, acc, 0, 0, 0);
        acc = __builtin_amdgcn_mfma_f32_16x16x32_bf16(a1, b1, acc, 0, 0, 0);
        s0 += __expf(acc[0] * 5.f);
        s1 += __expf(acc[1] * 5.f);
        s2 += __expf(acc[2] * 5.f);
        s3 += __expf(acc[3] * 5.f);
    }
#pragma unroll
    for (int m = 8; m; m >>= 1) {
        s0 += __shfl_xor(s0, m);
        s1 += __shfl_xor(s1, m);
        s2 += __shfl_xor(s2, m);
        s3 += __shfl_xor(s3, m);
    }
    if (rr == 0) {
        int row = rowbase + quad * 4;
        float* p = part + (size_t)row * nchunk + blockIdx.y;
        p[0] = s0;
        p[(size_t)nchunk] = s1;
        p[(size_t)2 * nchunk] = s2;
        p[(size_t)3 * nchunk] = s3;
    }
}

__global__ void combine_kernel(const float* __restrict__ part, int m, int nchunk, float pad,
                               float* __restrict__ acc, float coef) {
    int row = blockIdx.x * blockDim.x + threadIdx.x;
    if (row >= m) return;
    float S = 0.f;
    for (int c = 0; c < nchunk; c++) S += part[row * nchunk + c];
    float lse = __logf(S - pad);
    atomicAdd(acc, coef * lse);
}

__global__ void cat_kernel(const float* __restrict__ img, const float* __restrict__ txt,
                           float* __restrict__ out, int nrows) {
    int lane = threadIdx.x & 63;
    int row = (blockIdx.x * blockDim.x + threadIdx.x) >> 6;
    if (row >= nrows) return;
    float a = img[row * 64 + lane], b = txt[row * 64 + lane];
    float sa = a * a, sb = b * b;
#pragma unroll
    for (int msk = 32; msk; msk >>= 1) { sa += __shfl_xor(sa, msk); sb += __shfl_xor(sb, msk); }
    float ia = 1.f / fmaxf(sqrtf(sa), 1e-12f);
    float ib = 1.f / fmaxf(sqrtf(sb), 1e-12f);
    out[row * 64 + lane] += 0.02f * (a * ia + b * ib);
}

__global__ void loss_write_kernel(const float* __restrict__ acc, float* __restrict__ out) {
    out[0] = acc[0];
}

extern "C" void kernel_launch(void* const* d_in, const int* in_sizes, int n_in,
                              void* d_out, int out_size, void* d_ws, size_t ws_size,
                              hipStream_t stream) {
    const float* user_emb = (const float*)d_in[0];
    const float* item_emb = (const float*)d_in[1];
    const float* user_pre = (const float*)d_in[2];
    const float* item_pre = (const float*)d_in[3];
    const float* img_i = (const float*)d_in[4];
    const float* txt_i = (const float*)d_in[5];
    const float* img_u = (const float*)d_in[6];
    const float* txt_u = (const float*)d_in[7];
    const int* rows = (const int*)d_in[8];
    const int* cols = (const int*)d_in[9];
    const float* vals = (const float*)d_in[10];
    const float* ut = (const float*)d_in[11];
    const float* vt = (const float*)d_in[12];
    const float* u_mul_s = (const float*)d_in[13];
    const float* v_mul_s = (const float*)d_in[14];
    const int* uids = (const int*)d_in[15];
    const int* iids = (const int*)d_in[16];

    float* ws = (float*)d_ws;
    float* zu1 = ws + ZU1;
    float* zi1 = ws + ZI1;
    float2* edge = (float2*)(ws + EDGE);
    float* P = ws + P_OFF;
    float* Q = ws + Q_OFF;
    float* acc = ws + ACC_OFF;
    int* cnt = (int*)(ws + CNT_OFF);
    int* off = (int*)(ws + OFF_OFF);
    int* bcnt = (int*)(ws + BCNT_OFF);
    int* boff = (int*)(ws + BOFF_OFF);
    int* bsum = (int*)(ws + BSUM_OFF);
    float* eu0 = ws + EU0;
    float* ei0 = ws + EI0;
    float* part_u = ws + PART_U;
    float* part_i = ws + PART_I;
    int* bh = (int*)(ws + BH_OFF);
    int* bhp = (int*)(ws + BHP_OFF);
    float2* stage_sv = (float2*)(ws + STAGE_SV);
    short* ebu16 = (short*)(ws + EBU16);
    short* ebi16 = (short*)(ws + EBI16);
    short* gbu16 = (short*)(ws + GBU16);
    short* gbi16 = (short*)(ws + GBI16);

    float* out_u = (float*)d_out;
    float* out_i = out_u + (size_t)N_U * 64;
    float* out_loss = out_u + (size_t)(N_U + N_I) * 64;

    const int NB2 = (NBUCK + 255) / 256;  // 10 bucket-scan blocks

    // zero P,Q,acc only (cnt/off now written directly by place2)
    hipMemsetAsync(ws + P_OFF, 0, 704 * sizeof(float), stream);

    // ---- atomic-free CSR/CSC build ----
    // (bh/bhp overlay the edge region: dead before place2 writes edge;
    //  stage_sv overlays ZU1+ZI1: dead before spmm writes zu1/zi1)
    bhist_kernel<<<NPB, 256, 0, stream>>>(rows, cols, bh);
    col_scan_kernel<<<NB2, 256, 0, stream>>>(bh, bhp, bcnt);
    scan1_kernel<<<NB2, 256, 0, stream>>>(bcnt, bsum, NBUCK);
    scan2_kernel<<<1, 1024, 0, stream>>>(bsum, NB2);
    scan3_kernel<<<NB2, 256, 0, stream>>>(bcnt, bsum, boff, NBUCK);
    bucket_place_kernel<<<NPB, 256, 0, stream>>>(rows, cols, vals, boff, bhp, stage_sv);
    place2_kernel<<<NBUCK, 256, 0, stream>>>(stage_sv, boff, bcnt, off, cnt, edge);

    // E0 = pre + emb
    ew_add_kernel<<<6250, 256, 0, stream>>>((const float4*)user_emb, (const float4*)user_pre,
                                            (float4*)eu0, 1600000);
    ew_add_kernel<<<3125, 256, 0, stream>>>((const float4*)item_emb, (const float4*)item_pre,
                                            (float4*)ei0, 800000);
    // layer-1 rank reductions
    rank_kernel<<<256, 256, 0, stream>>>(ei0, vt, P, N_I);
    rank_kernel<<<256, 256, 0, stream>>>(eu0, ut, Q, N_U);
    // layer-1 SpMM (CSR, no atomics; staging sv now dead -> zu1/zi1 regions free)
    spmm_csr_kernel<<<N_U / 4, 256, 0, stream>>>(edge, off, cnt, 0, ei0, zu1, 1.f, 0, N_U);
    spmm_csr_kernel<<<N_I / 4, 256, 0, stream>>>(edge, off, cnt, N_U, eu0, zi1, 1.f, 0, N_I);
    // layer-2 rank reductions
    rank_kernel<<<256, 256, 0, stream>>>(zi1, vt, P, N_I);
    rank_kernel<<<256, 256, 0, stream>>>(zu1, ut, Q, N_U);
    // out = (E0 + Z1)/3, then layer-2 SpMM accumulates Z2/3 into out
    pre_out_kernel<<<6250, 256, 0, stream>>>((const float4*)eu0, (const float4*)zu1,
                                             (float4*)out_u, 1600000);
    pre_out_kernel<<<3125, 256, 0, stream>>>((const float4*)ei0, (const float4*)zi1,
                                             (float4*)out_i, 800000);
    spmm_csr_kernel<<<N_U / 4, 256, 0, stream>>>(edge, off, cnt, 0, zi1, out_u, 1.f / 3.f, 1,
                                                 N_U);
    spmm_csr_kernel<<<N_I / 4, 256, 0, stream>>>(edge, off, cnt, N_U, zu1, out_i, 1.f / 3.f, 1,
                                                 N_I);
    // bf16 copies of E (overlay in dead zu1 region; zero-padded tail rows)
    conv_bf16_kernel<<<(NPAD_U * 64 + 255) / 256, 256, 0, stream>>>(out_u, ebu16, N_U * 64,
                                                                   NPAD_U * 64);
    conv_bf16_kernel<<<(NPAD_I * 64 + 255) / 256, 256, 0, stream>>>(out_i, ebi16, N_I * 64,
                                                                   NPAD_I * 64);
    // sampled G rows (bf16) + pos term (fp32)
    gather_kernel<<<M_U / 4, 256, 0, stream>>>(uids, M_U, eu0, P, u_mul_s, out_u, gbu16, acc,
                                               -4.f / M_U);
    gather_kernel<<<M_I / 4, 256, 0, stream>>>(iids, M_I, ei0, Q, v_mul_s, out_i, gbi16, acc,
                                               -4.f / M_I);
    // neg term: MFMA exp-sum
    dim3 gu(M_U / 64, NCH_U);
    neg_mfma_kernel<<<gu, 256, 0, stream>>>(gbu16, ebu16, part_u, NCH_U);
    dim3 gi(M_I / 64, NCH_I);
    neg_mfma_kernel<<<gi, 256, 0, stream>>>(gbi16, ebi16, part_i, NCH_I);
    combine_kernel<<<(M_U + 255) / 256, 256, 0, stream>>>(part_u, M_U, NCH_U,
                                                          (float)(NPAD_U - N_U), acc, 4.f / M_U);
    combine_kernel<<<(M_I + 255) / 256, 256, 0, stream>>>(part_i, M_I, NCH_I,
                                                          (float)(NPAD_I - N_I), acc, 4.f / M_I);
    // cat-rate terms (after loss consumed E from d_out)
    cat_kernel<<<(N_U * 64 + 255) / 256, 256, 0, stream>>>(img_u, txt_u, out_u, N_U);
    cat_kernel<<<(N_I * 64 + 255) / 256, 256, 0, stream>>>(img_i, txt_i, out_i, N_I);
    loss_write_kernel<<<1, 1, 0, stream>>>(acc, out_loss);
}

// Round 2
// 1194.054 us; speedup vs baseline: 1.3353x; 1.1869x over previous
//
#include <hip/hip_runtime.h>
#include <cstdint>

#define N_U 100000
#define N_I 50000
#define DIM 64
#define RANK 5
#define NNZ_ 2000000
#define M_U 2048
#define M_I 4096
#define NSEG 150000   // N_U + N_I combined segment count
#define BSH 6         // bucket = seg >> 6  (64 segments per bucket)
#define NBUCK 2344    // ceil(NSEG/64)
#define NPB 512       // place blocks
#define CH 3907       // edges per place block (ceil(NNZ_/NPB))

// neg-GEMM tiling
#define CPC 3136
#define CPW 784       // CPC/4, columns per wave
#define NCH_U 32
#define NCH_I 16
#define NPAD_U (CPC * NCH_U)
#define NPAD_I (CPC * NCH_I)

typedef __attribute__((ext_vector_type(8))) short short8;
typedef __attribute__((ext_vector_type(4))) float floatx4;

// ---- workspace layout (float offsets) ----
static constexpr size_t ZU1 = 0;                       // 6.4M
static constexpr size_t ZI1 = 6400000;                 // 3.2M
static constexpr size_t EDGE = 9600000;                // 4M float2 = 8M floats
static constexpr size_t P_OFF = 17600000;              // 320
static constexpr size_t Q_OFF = 17600320;              // 320
static constexpr size_t ACC_OFF = 17600640;            // 1 (pad to 704)
static constexpr size_t CNT_OFF = 17600704;            // 150000 ints
static constexpr size_t OFF_OFF = 17750704;            // 150016 ints
static constexpr size_t BCNT_OFF = 17900720;           // NBUCK ints
static constexpr size_t BOFF_OFF = 17910144;           // NBUCK ints
static constexpr size_t BSUM_OFF = 17919552;           // 1024 ints
static constexpr size_t EU0 = 17920576;                // 6.4M
static constexpr size_t EI0 = EU0 + 6400000;           // 3.2M
static constexpr size_t PART_U = EI0 + 3200000;        // 2048*128 = 262144
static constexpr size_t PART_I = PART_U + (size_t)M_U * NCH_U * 4;  // 4096*64 = 262144
// end = PART_I + M_I*NCH_I*4 = 28,044,864 floats = 112.2 MB (< 115.7 MB cap)
// ---- staging overlays, live ONLY during CSR build (before spmm / before place2) ----
static constexpr size_t STAGE_SV = 0;                  // 4M float2 over ZU1+ZI1
static constexpr size_t BH_OFF = EDGE;                 // NPB*NBUCK ints, dead before place2
static constexpr size_t BHP_OFF = EDGE + (size_t)NPB * NBUCK;  // NPB*NBUCK ints
// BH+BHP = 2*512*2344 = 2,400,256 floats < 8M edge region ✓
// ---- bf16 overlay inside ZU1 (zu1/zi1 dead after layer-2 spmm) ----
static constexpr size_t EBU16 = 0;                     // 3,211,264 fl
static constexpr size_t EBI16 = 3211264;               // 1,605,632 fl
static constexpr size_t GBU16 = EBI16 + 1605632;       // 65,536 fl
static constexpr size_t GBI16 = GBU16 + 65536;         // 131,072 fl -> end 5,013,504 < 6.4M

static __device__ __forceinline__ short f2bf(float x) {
    unsigned u = __builtin_bit_cast(unsigned, x);
    unsigned r = (u + 0x7fffu + ((u >> 16) & 1u)) >> 16;
    return (short)r;
}

__global__ void ew_add_kernel(const float4* __restrict__ a, const float4* __restrict__ b,
                              float4* __restrict__ o, int n) {
    int i = blockIdx.x * blockDim.x + threadIdx.x;
    if (i < n) {
        float4 x = a[i], y = b[i];
        o[i] = make_float4(x.x + y.x, x.y + y.y, x.z + y.z, x.w + y.w);
    }
}

// ---------- atomic-free CSR/CSC build ----------
// phase 1: per-block LDS bucket histogram, dense writeout bh[block][bucket]
__global__ __launch_bounds__(256) void bhist_kernel(const int* __restrict__ rows,
                                                    const int* __restrict__ cols,
                                                    int* __restrict__ bh) {
    __shared__ int h[NBUCK];
    for (int i = threadIdx.x; i < NBUCK; i += 256) h[i] = 0;
    __syncthreads();
    int b = blockIdx.x;
    int lo = b * CH, hi = min(lo + CH, NNZ_);
    for (int e = lo + threadIdx.x; e < hi; e += 256) {
        atomicAdd(&h[rows[e] >> BSH], 1);
        atomicAdd(&h[(N_U + cols[e]) >> BSH], 1);
    }
    __syncthreads();
    for (int i = threadIdx.x; i < NBUCK; i += 256) bh[(size_t)b * NBUCK + i] = h[i];
}

// phase 2: coalesced column scan: one thread per bucket, serial over NPB blocks.
__global__ __launch_bounds__(256) void col_scan_kernel(const int* __restrict__ bh,
                                                       int* __restrict__ bhp,
                                                       int* __restrict__ bcnt) {
    int j = blockIdx.x * 256 + threadIdx.x;
    if (j >= NBUCK) return;
    int run = 0;
#pragma unroll 8
    for (int b = 0; b < NPB; b++) {
        int v = bh[(size_t)b * NBUCK + j];
        bhp[(size_t)b * NBUCK + j] = run;
        run += v;
    }
    bcnt[j] = run;
}

__global__ void scan1_kernel(const int* __restrict__ cnt, int* __restrict__ bsum, int n) {
    int i = blockIdx.x * 256 + threadIdx.x;
    int v = (i < n) ? cnt[i] : 0;
#pragma unroll
    for (int off = 32; off; off >>= 1) v += __shfl_down(v, off);
    __shared__ int ls[4];
    int lane = threadIdx.x & 63, w = threadIdx.x >> 6;
    if (lane == 0) ls[w] = v;
    __syncthreads();
    if (threadIdx.x == 0) bsum[blockIdx.x] = ls[0] + ls[1] + ls[2] + ls[3];
}

__global__ void scan2_kernel(int* __restrict__ bsum, int nb) {
    __shared__ int s[1024];
    int t = threadIdx.x;
    s[t] = (t < nb) ? bsum[t] : 0;
    __syncthreads();
    for (int off = 1; off < 1024; off <<= 1) {
        int v = (t >= off) ? s[t - off] : 0;
        __syncthreads();
        s[t] += v;
        __syncthreads();
    }
    if (t < nb) bsum[t] = (t == 0) ? 0 : s[t - 1];
}

__global__ void scan3_kernel(const int* __restrict__ cnt, const int* __restrict__ bsum,
                             int* __restrict__ off, int n) {
    __shared__ int s[256];
    int i = blockIdx.x * 256 + threadIdx.x;
    int t = threadIdx.x;
    int c = (i < n) ? cnt[i] : 0;
    s[t] = c;
    __syncthreads();
    for (int o = 1; o < 256; o <<= 1) {
        int v = (t >= o) ? s[t - o] : 0;
        __syncthreads();
        s[t] += v;
        __syncthreads();
    }
    if (i < n) off[i] = bsum[blockIdx.x] + s[t] - c;
}

// phase 3: deterministic placement into bucket-grouped staging (no global atomics).
// entry = (idx | (seg&63)<<20, val) -- idx < 2^20, 6-bit nibble recovers segment in place2.
__global__ __launch_bounds__(256) void bucket_place_kernel(
    const int* __restrict__ rows, const int* __restrict__ cols, const float* __restrict__ vals,
    const int* __restrict__ boff, const int* __restrict__ bhp, float2* __restrict__ sv) {
    __shared__ int h[NBUCK];
    for (int i = threadIdx.x; i < NBUCK; i += 256) h[i] = 0;
    __syncthreads();
    int b = blockIdx.x;
    int lo = b * CH, hi = min(lo + CH, NNZ_);
    const int* bhpb = bhp + (size_t)b * NBUCK;
    for (int e = lo + threadIdx.x; e < hi; e += 256) {
        int r = rows[e], c = cols[e];
        float v = vals[e];
        int bu = r >> BSH;
        int ru = atomicAdd(&h[bu], 1);
        sv[boff[bu] + bhpb[bu] + ru] = make_float2(__int_as_float(c | ((r & 63) << 20)), v);
        int sI = N_U + c;
        int bi = sI >> BSH;
        int ri = atomicAdd(&h[bi], 1);
        sv[boff[bi] + bhpb[bi] + ri] = make_float2(__int_as_float(r | ((sI & 63) << 20)), v);
    }
}

// phase 4: one block per bucket: exact CSR placement of its entries
__global__ __launch_bounds__(256) void place2_kernel(const float2* __restrict__ sv,
                                                     const int* __restrict__ boff,
                                                     const int* __restrict__ bcnt,
                                                     int* __restrict__ off, int* __restrict__ cnt,
                                                     float2* __restrict__ edge) {
    int b = blockIdx.x;
    int start = boff[b], n = bcnt[b];
    __shared__ int h[64], hs[64], hc[64];
    if (threadIdx.x < 64) { h[threadIdx.x] = 0; hc[threadIdx.x] = 0; }
    __syncthreads();
    for (int i = start + threadIdx.x; i < start + n; i += 256) {
        int packed = __float_as_int(sv[i].x);
        atomicAdd(&h[(packed >> 20) & 63], 1);
    }
    __syncthreads();
    if (threadIdx.x == 0) {
        int run = 0;
#pragma unroll
        for (int k = 0; k < 64; k++) { hs[k] = run; run += h[k]; }
    }
    __syncthreads();
    if (threadIdx.x < 64) {
        int seg = b * 64 + threadIdx.x;
        if (seg < NSEG) {
            cnt[seg] = h[threadIdx.x];
            off[seg] = start + hs[threadIdx.x] + h[threadIdx.x];  // END offsets (spmm convention)
        }
    }
    for (int i = start + threadIdx.x; i < start + n; i += 256) {
        float2 p = sv[i];
        int packed = __float_as_int(p.x);
        int s = (packed >> 20) & 63;
        int r = atomicAdd(&hc[s], 1);
        edge[start + hs[s] + r] = make_float2(__int_as_float(packed & 0xFFFFF), p.y);
    }
}

// wave-per-row CSR SpMM; off[] holds END offsets, range = [end-cnt, end)
__global__ __launch_bounds__(256) void spmm_csr_kernel(
    const float2* __restrict__ edge, const int* __restrict__ off, const int* __restrict__ cnt,
    int base, const float* __restrict__ Esrc, float* __restrict__ out, float scale, int accum,
    int nrows) {
    int lane = threadIdx.x & 63;
    int row = (blockIdx.x * blockDim.x + threadIdx.x) >> 6;
    if (row >= nrows) return;
    int end = off[base + row];
    int n = cnt[base + row];
    int e = end - n;
    float acc = 0.f;
    for (; e + 4 <= end; e += 4) {
        float2 p0 = edge[e], p1 = edge[e + 1], p2 = edge[e + 2], p3 = edge[e + 3];
        float g0 = Esrc[(size_t)__float_as_int(p0.x) * 64 + lane];
        float g1 = Esrc[(size_t)__float_as_int(p1.x) * 64 + lane];
        float g2 = Esrc[(size_t)__float_as_int(p2.x) * 64 + lane];
        float g3 = Esrc[(size_t)__float_as_int(p3.x) * 64 + lane];
        acc = __builtin_fmaf(p0.y, g0, acc);
        acc = __builtin_fmaf(p1.y, g1, acc);
        acc = __builtin_fmaf(p2.y, g2, acc);
        acc = __builtin_fmaf(p3.y, g3, acc);
    }
    for (; e < end; e++) {
        float2 p = edge[e];
        acc = __builtin_fmaf(p.y, Esrc[(size_t)__float_as_int(p.x) * 64 + lane], acc);
    }
    size_t o = (size_t)row * 64 + lane;
    if (accum) out[o] += scale * acc;
    else out[o] = acc;
}

__global__ void rank_kernel(const float* __restrict__ X, const float* __restrict__ W,
                            float* __restrict__ P, int n) {
    int lane = threadIdx.x & 63;
    int wave = (blockIdx.x * blockDim.x + threadIdx.x) >> 6;
    int nw = (gridDim.x * blockDim.x) >> 6;
    float acc[RANK] = {0.f, 0.f, 0.f, 0.f, 0.f};
    for (int i = wave; i < n; i += nw) {
        float x = X[i * 64 + lane];
#pragma unroll
        for (int r = 0; r < RANK; r++) acc[r] = __builtin_fmaf(W[r * n + i], x, acc[r]);
    }
#pragma unroll
    for (int r = 0; r < RANK; r++) atomicAdd(&P[r * 64 + lane], acc[r]);
}

__global__ void pre_out_kernel(const float4* __restrict__ a, const float4* __restrict__ b,
                               float4* __restrict__ o, int n) {
    int i = blockIdx.x * blockDim.x + threadIdx.x;
    if (i < n) {
        float4 x = a[i], y = b[i];
        const float s = 1.f / 3.f;
        o[i] = make_float4((x.x + y.x) * s, (x.y + y.y) * s, (x.z + y.z) * s, (x.w + y.w) * s);
    }
}

__global__ void conv_bf16_kernel(const float* __restrict__ E, short* __restrict__ B, int n64,
                                 int npad64) {
    int i = blockIdx.x * blockDim.x + threadIdx.x;
    if (i < npad64) B[i] = (i < n64) ? f2bf(E[i]) : (short)0;
}

__global__ void gather_kernel(const int* __restrict__ ids, int m, const float* __restrict__ E0,
                              const float* __restrict__ PQ, const float* __restrict__ mulS,
                              const float* __restrict__ Eout, short* __restrict__ Gb,
                              float* __restrict__ acc, float coef) {
    int lane = threadIdx.x & 63;
    int k = (blockIdx.x * blockDim.x + threadIdx.x) >> 6;
    if (k >= m) return;
    int u = ids[k];
    float g = E0[u * 64 + lane];
#pragma unroll
    for (int r = 0; r < RANK; r++) g = __builtin_fmaf(mulS[u * RANK + r], PQ[r * 64 + lane], g);
    g *= (1.f / 3.f);
    Gb[k * 64 + lane] = f2bf(g);
    float d = g * Eout[u * 64 + lane];
#pragma unroll
    for (int off = 32; off; off >>= 1) d += __shfl_down(d, off);
    if (lane == 0) {
        float t = fminf(fmaxf(d * 5.f, -5.f), 5.f);
        atomicAdd(acc, coef * t);
    }
}

// M-register-blocked neg-GEMM: each wave holds A for all 64 block rows (4 groups),
// sweeps CPW columns; per B-load-pair we issue 8 MFMAs + 16 exp-accumulates.
// part layout: [row][nchunk] with nchunk = NCH*4 (each wave owns one chunk-column).
__global__ __launch_bounds__(256) void neg_mfma_kernel(const short* __restrict__ G16,
                                                       const short* __restrict__ E16,
                                                       float* __restrict__ part, int nchunk) {
    int lane = threadIdx.x & 63;
    int wave = threadIdx.x >> 6;
    int quad = lane >> 4;
    int rr = lane & 15;
    int rowbase = blockIdx.x * 64;
    short8 a0[4], a1[4];
#pragma unroll
    for (int g = 0; g < 4; g++) {
        const short8* ga = (const short8*)(G16 + (size_t)(rowbase + g * 16 + rr) * 64 + quad * 8);
        a0[g] = ga[0];
        a1[g] = ga[4];
    }
    int c0 = blockIdx.y * CPC + wave * CPW;
    float s[16];
#pragma unroll
    for (int i = 0; i < 16; i++) s[i] = 0.f;
    for (int ct = 0; ct < CPW; ct += 16) {
        const short8* eb = (const short8*)(E16 + (size_t)(c0 + ct + rr) * 64 + quad * 8);
        short8 b0 = eb[0];
        short8 b1 = eb[4];
#pragma unroll
        for (int g = 0; g < 4; g++) {
            floatx4 acc = {0.f, 0.f, 0.f, 0.f};
            acc = __builtin_amdgcn_mfma_f32_16x16x32_bf16(a0[g], b0, acc, 0, 0, 0);
            acc = __builtin_amdgcn_mfma_f32_16x16x32_bf16(a1[g], b1, acc, 0, 0, 0);
            s[g * 4 + 0] += __expf(acc[0] * 5.f);
            s[g * 4 + 1] += __expf(acc[1] * 5.f);
            s[g * 4 + 2] += __expf(acc[2] * 5.f);
            s[g * 4 + 3] += __expf(acc[3] * 5.f);
        }
    }
#pragma unroll
    for (int m = 8; m; m >>= 1) {
#pragma unroll
        for (int i = 0; i < 16; i++) s[i] += __shfl_xor(s[i], m);
    }
    if (rr == 0) {
        int col = blockIdx.y * 4 + wave;
#pragma unroll
        for (int g = 0; g < 4; g++) {
#pragma unroll
            for (int j = 0; j < 4; j++) {
                int row = rowbase + g * 16 + quad * 4 + j;
                part[(size_t)row * nchunk + col] = s[g * 4 + j];
            }
        }
    }
}

__global__ void combine_kernel(const float* __restrict__ part, int m, int nchunk, float pad,
                               float* __restrict__ acc, float coef) {
    int row = blockIdx.x * blockDim.x + threadIdx.x;
    if (row >= m) return;
    float S = 0.f;
    for (int c = 0; c < nchunk; c++) S += part[row * nchunk + c];
    float lse = __logf(S - pad);
    atomicAdd(acc, coef * lse);
}

__global__ void cat_kernel(const float* __restrict__ img, const float* __restrict__ txt,
                           float* __restrict__ out, int nrows) {
    int lane = threadIdx.x & 63;
    int row = (blockIdx.x * blockDim.x + threadIdx.x) >> 6;
    if (row >= nrows) return;
    float a = img[row * 64 + lane], b = txt[row * 64 + lane];
    float sa = a * a, sb = b * b;
#pragma unroll
    for (int msk = 32; msk; msk >>= 1) { sa += __shfl_xor(sa, msk); sb += __shfl_xor(sb, msk); }
    float ia = 1.f / fmaxf(sqrtf(sa), 1e-12f);
    float ib = 1.f / fmaxf(sqrtf(sb), 1e-12f);
    out[row * 64 + lane] += 0.02f * (a * ia + b * ib);
}

__global__ void loss_write_kernel(const float* __restrict__ acc, float* __restrict__ out) {
    out[0] = acc[0];
}

extern "C" void kernel_launch(void* const* d_in, const int* in_sizes, int n_in,
                              void* d_out, int out_size, void* d_ws, size_t ws_size,
                              hipStream_t stream) {
    const float* user_emb = (const float*)d_in[0];
    const float* item_emb = (const float*)d_in[1];
    const float* user_pre = (const float*)d_in[2];
    const float* item_pre = (const float*)d_in[3];
    const float* img_i = (const float*)d_in[4];
    const float* txt_i = (const float*)d_in[5];
    const float* img_u = (const float*)d_in[6];
    const float* txt_u = (const float*)d_in[7];
    const int* rows = (const int*)d_in[8];
    const int* cols = (const int*)d_in[9];
    const float* vals = (const float*)d_in[10];
    const float* ut = (const float*)d_in[11];
    const float* vt = (const float*)d_in[12];
    const float* u_mul_s = (const float*)d_in[13];
    const float* v_mul_s = (const float*)d_in[14];
    const int* uids = (const int*)d_in[15];
    const int* iids = (const int*)d_in[16];

    float* ws = (float*)d_ws;
    float* zu1 = ws + ZU1;
    float* zi1 = ws + ZI1;
    float2* edge = (float2*)(ws + EDGE);
    float* P = ws + P_OFF;
    float* Q = ws + Q_OFF;
    float* acc = ws + ACC_OFF;
    int* cnt = (int*)(ws + CNT_OFF);
    int* off = (int*)(ws + OFF_OFF);
    int* bcnt = (int*)(ws + BCNT_OFF);
    int* boff = (int*)(ws + BOFF_OFF);
    int* bsum = (int*)(ws + BSUM_OFF);
    float* eu0 = ws + EU0;
    float* ei0 = ws + EI0;
    float* part_u = ws + PART_U;
    float* part_i = ws + PART_I;
    int* bh = (int*)(ws + BH_OFF);
    int* bhp = (int*)(ws + BHP_OFF);
    float2* stage_sv = (float2*)(ws + STAGE_SV);
    short* ebu16 = (short*)(ws + EBU16);
    short* ebi16 = (short*)(ws + EBI16);
    short* gbu16 = (short*)(ws + GBU16);
    short* gbi16 = (short*)(ws + GBI16);

    float* out_u = (float*)d_out;
    float* out_i = out_u + (size_t)N_U * 64;
    float* out_loss = out_u + (size_t)(N_U + N_I) * 64;

    const int NB2 = (NBUCK + 255) / 256;  // 10 bucket-scan blocks

    // zero P,Q,acc only (cnt/off now written directly by place2)
    hipMemsetAsync(ws + P_OFF, 0, 704 * sizeof(float), stream);

    // ---- atomic-free CSR/CSC build ----
    bhist_kernel<<<NPB, 256, 0, stream>>>(rows, cols, bh);
    col_scan_kernel<<<NB2, 256, 0, stream>>>(bh, bhp, bcnt);
    scan1_kernel<<<NB2, 256, 0, stream>>>(bcnt, bsum, NBUCK);
    scan2_kernel<<<1, 1024, 0, stream>>>(bsum, NB2);
    scan3_kernel<<<NB2, 256, 0, stream>>>(bcnt, bsum, boff, NBUCK);
    bucket_place_kernel<<<NPB, 256, 0, stream>>>(rows, cols, vals, boff, bhp, stage_sv);
    place2_kernel<<<NBUCK, 256, 0, stream>>>(stage_sv, boff, bcnt, off, cnt, edge);

    // E0 = pre + emb
    ew_add_kernel<<<6250, 256, 0, stream>>>((const float4*)user_emb, (const float4*)user_pre,
                                            (float4*)eu0, 1600000);
    ew_add_kernel<<<3125, 256, 0, stream>>>((const float4*)item_emb, (const float4*)item_pre,
                                            (float4*)ei0, 800000);
    // layer-1 rank reductions
    rank_kernel<<<256, 256, 0, stream>>>(ei0, vt, P, N_I);
    rank_kernel<<<256, 256, 0, stream>>>(eu0, ut, Q, N_U);
    // layer-1 SpMM
    spmm_csr_kernel<<<N_U / 4, 256, 0, stream>>>(edge, off, cnt, 0, ei0, zu1, 1.f, 0, N_U);
    spmm_csr_kernel<<<N_I / 4, 256, 0, stream>>>(edge, off, cnt, N_U, eu0, zi1, 1.f, 0, N_I);
    // layer-2 rank reductions
    rank_kernel<<<256, 256, 0, stream>>>(zi1, vt, P, N_I);
    rank_kernel<<<256, 256, 0, stream>>>(zu1, ut, Q, N_U);
    // out = (E0 + Z1)/3, then layer-2 SpMM accumulates Z2/3 into out
    pre_out_kernel<<<6250, 256, 0, stream>>>((const float4*)eu0, (const float4*)zu1,
                                             (float4*)out_u, 1600000);
    pre_out_kernel<<<3125, 256, 0, stream>>>((const float4*)ei0, (const float4*)zi1,
                                             (float4*)out_i, 800000);
    spmm_csr_kernel<<<N_U / 4, 256, 0, stream>>>(edge, off, cnt, 0, zi1, out_u, 1.f / 3.f, 1,
                                                 N_U);
    spmm_csr_kernel<<<N_I / 4, 256, 0, stream>>>(edge, off, cnt, N_U, zu1, out_i, 1.f / 3.f, 1,
                                                 N_I);
    // bf16 copies of E (overlay in dead zu1 region; zero-padded tail rows)
    conv_bf16_kernel<<<(NPAD_U * 64 + 255) / 256, 256, 0, stream>>>(out_u, ebu16, N_U * 64,
                                                                   NPAD_U * 64);
    conv_bf16_kernel<<<(NPAD_I * 64 + 255) / 256, 256, 0, stream>>>(out_i, ebi16, N_I * 64,
                                                                   NPAD_I * 64);
    // sampled G rows (bf16) + pos term (fp32)
    gather_kernel<<<M_U / 4, 256, 0, stream>>>(uids, M_U, eu0, P, u_mul_s, out_u, gbu16, acc,
                                               -4.f / M_U);
    gather_kernel<<<M_I / 4, 256, 0, stream>>>(iids, M_I, ei0, Q, v_mul_s, out_i, gbi16, acc,
                                               -4.f / M_I);
    // neg term: MFMA exp-sum (4 chunk-columns per blockIdx.y: one per wave)
    dim3 gu(M_U / 64, NCH_U);
    neg_mfma_kernel<<<gu, 256, 0, stream>>>(gbu16, ebu16, part_u, NCH_U * 4);
    dim3 gi(M_I / 64, NCH_I);
    neg_mfma_kernel<<<gi, 256, 0, stream>>>(gbi16, ebi16, part_i, NCH_I * 4);
    combine_kernel<<<(M_U + 255) / 256, 256, 0, stream>>>(part_u, M_U, NCH_U * 4,
                                                          (float)(NPAD_U - N_U), acc, 4.f / M_U);
    combine_kernel<<<(M_I + 255) / 256, 256, 0, stream>>>(part_i, M_I, NCH_I * 4,
                                                          (float)(NPAD_I - N_I), acc, 4.f / M_I);
    // cat-rate terms (after loss consumed E from d_out)
    cat_kernel<<<(N_U * 64 + 255) / 256, 256, 0, stream>>>(img_u, txt_u, out_u, N_U);
    cat_kernel<<<(N_I * 64 + 255) / 256, 256, 0, stream>>>(img_i, txt_i, out_i, N_I);
    loss_write_kernel<<<1, 1, 0, stream>>>(acc, out_loss);
}

// Round 3
// 1165.809 us; speedup vs baseline: 1.3677x; 1.0242x over previous
//
#include <hip/hip_runtime.h>
#include <cstdint>

#define N_U 100000
#define N_I 50000
#define DIM 64
#define RANK 5
#define NNZ_ 2000000
#define M_U 2048
#define M_I 4096
#define NSEG 150000   // N_U + N_I combined segment count
#define BSH 8         // bucket = seg >> 8  (256 segments per bucket)
#define NBUCK 586     // ceil(NSEG/256)
#define NPB 512       // place blocks
#define CH 3907       // edges per place block (ceil(NNZ_/NPB))

// neg-GEMM tiling
#define CPC 3136
#define CPW 784       // CPC/4, columns per wave
#define NCH_U 32
#define NCH_I 16
#define NPAD_U (CPC * NCH_U)
#define NPAD_I (CPC * NCH_I)

typedef __attribute__((ext_vector_type(8))) short short8;
typedef __attribute__((ext_vector_type(4))) float floatx4;

// ---- workspace layout (float offsets) ----
static constexpr size_t ZU1 = 0;                       // 6.4M
static constexpr size_t ZI1 = 6400000;                 // 3.2M
static constexpr size_t EDGE = 9600000;                // 4M float2 = 8M floats
static constexpr size_t P_OFF = 17600000;              // 320
static constexpr size_t Q_OFF = 17600320;              // 320
static constexpr size_t ACC_OFF = 17600640;            // 1 (pad to 704)
static constexpr size_t CNT_OFF = 17600704;            // 150000 ints
static constexpr size_t OFF_OFF = 17750704;            // 150016 ints
static constexpr size_t BCNT_OFF = 17900720;           // NBUCK ints
static constexpr size_t BOFF_OFF = 17910144;           // NBUCK ints
static constexpr size_t BSUM_OFF = 17919552;           // 1024 ints
static constexpr size_t EU0 = 17920576;                // 6.4M
static constexpr size_t EI0 = EU0 + 6400000;           // 3.2M
static constexpr size_t PART_U = EI0 + 3200000;        // 2048*128 = 262144
static constexpr size_t PART_I = PART_U + (size_t)M_U * NCH_U * 4;  // 4096*64 = 262144
// end = PART_I + M_I*NCH_I*4 = 28,044,864 floats = 112.2 MB (< 115.7 MB cap)
// ---- staging overlays, live ONLY during CSR build (before spmm / before place2) ----
static constexpr size_t STAGE_SV = 0;                  // 4M float2 over ZU1+ZI1
static constexpr size_t BH_OFF = EDGE;                 // NPB*NBUCK ints, dead before place2
static constexpr size_t BHP_OFF = EDGE + (size_t)NPB * NBUCK;  // NPB*NBUCK ints
// BH+BHP = 2*512*586 = 600,064 floats < 8M edge region ✓
// ---- bf16 overlay inside ZU1 (zu1/zi1 dead after layer-2 spmm) ----
static constexpr size_t EBU16 = 0;                     // 3,211,264 fl
static constexpr size_t EBI16 = 3211264;               // 1,605,632 fl
static constexpr size_t GBU16 = EBI16 + 1605632;       // 65,536 fl
static constexpr size_t GBI16 = GBU16 + 65536;         // 131,072 fl -> end 5,013,504 < 6.4M

static __device__ __forceinline__ short f2bf(float x) {
    unsigned u = __builtin_bit_cast(unsigned, x);
    unsigned r = (u + 0x7fffu + ((u >> 16) & 1u)) >> 16;
    return (short)r;
}

__global__ void ew_add_kernel(const float4* __restrict__ a, const float4* __restrict__ b,
                              float4* __restrict__ o, int n) {
    int i = blockIdx.x * blockDim.x + threadIdx.x;
    if (i < n) {
        float4 x = a[i], y = b[i];
        o[i] = make_float4(x.x + y.x, x.y + y.y, x.z + y.z, x.w + y.w);
    }
}

// ---------- atomic-free CSR/CSC build ----------
// phase 1: per-block LDS bucket histogram, dense writeout bh[block][bucket]
__global__ __launch_bounds__(256) void bhist_kernel(const int* __restrict__ rows,
                                                    const int* __restrict__ cols,
                                                    int* __restrict__ bh) {
    __shared__ int h[NBUCK];
    for (int i = threadIdx.x; i < NBUCK; i += 256) h[i] = 0;
    __syncthreads();
    int b = blockIdx.x;
    int lo = b * CH, hi = min(lo + CH, NNZ_);
    for (int e = lo + threadIdx.x; e < hi; e += 256) {
        atomicAdd(&h[rows[e] >> BSH], 1);
        atomicAdd(&h[(N_U + cols[e]) >> BSH], 1);
    }
    __syncthreads();
    for (int i = threadIdx.x; i < NBUCK; i += 256) bh[(size_t)b * NBUCK + i] = h[i];
}

// phase 2: coalesced column scan: one thread per bucket, serial over NPB blocks.
__global__ __launch_bounds__(256) void col_scan_kernel(const int* __restrict__ bh,
                                                       int* __restrict__ bhp,
                                                       int* __restrict__ bcnt) {
    int j = blockIdx.x * 256 + threadIdx.x;
    if (j >= NBUCK) return;
    int run = 0;
#pragma unroll 16
    for (int b = 0; b < NPB; b++) {
        int v = bh[(size_t)b * NBUCK + j];
        bhp[(size_t)b * NBUCK + j] = run;
        run += v;
    }
    bcnt[j] = run;
}

__global__ void scan1_kernel(const int* __restrict__ cnt, int* __restrict__ bsum, int n) {
    int i = blockIdx.x * 256 + threadIdx.x;
    int v = (i < n) ? cnt[i] : 0;
#pragma unroll
    for (int off = 32; off; off >>= 1) v += __shfl_down(v, off);
    __shared__ int ls[4];
    int lane = threadIdx.x & 63, w = threadIdx.x >> 6;
    if (lane == 0) ls[w] = v;
    __syncthreads();
    if (threadIdx.x == 0) bsum[blockIdx.x] = ls[0] + ls[1] + ls[2] + ls[3];
}

__global__ void scan2_kernel(int* __restrict__ bsum, int nb) {
    __shared__ int s[1024];
    int t = threadIdx.x;
    s[t] = (t < nb) ? bsum[t] : 0;
    __syncthreads();
    for (int off = 1; off < 1024; off <<= 1) {
        int v = (t >= off) ? s[t - off] : 0;
        __syncthreads();
        s[t] += v;
        __syncthreads();
    }
    if (t < nb) bsum[t] = (t == 0) ? 0 : s[t - 1];
}

__global__ void scan3_kernel(const int* __restrict__ cnt, const int* __restrict__ bsum,
                             int* __restrict__ off, int n) {
    __shared__ int s[256];
    int i = blockIdx.x * 256 + threadIdx.x;
    int t = threadIdx.x;
    int c = (i < n) ? cnt[i] : 0;
    s[t] = c;
    __syncthreads();
    for (int o = 1; o < 256; o <<= 1) {
        int v = (t >= o) ? s[t - o] : 0;
        __syncthreads();
        s[t] += v;
        __syncthreads();
    }
    if (i < n) off[i] = bsum[blockIdx.x] + s[t] - c;
}

// phase 3: deterministic placement into bucket-grouped staging (no global atomics).
// entry = (idx | (seg&255)<<20, val) -- idx < 2^20, 8-bit tag recovers segment in place2.
__global__ __launch_bounds__(256) void bucket_place_kernel(
    const int* __restrict__ rows, const int* __restrict__ cols, const float* __restrict__ vals,
    const int* __restrict__ boff, const int* __restrict__ bhp, float2* __restrict__ sv) {
    __shared__ int h[NBUCK];
    for (int i = threadIdx.x; i < NBUCK; i += 256) h[i] = 0;
    __syncthreads();
    int b = blockIdx.x;
    int lo = b * CH, hi = min(lo + CH, NNZ_);
    const int* bhpb = bhp + (size_t)b * NBUCK;
    for (int e = lo + threadIdx.x; e < hi; e += 256) {
        int r = rows[e], c = cols[e];
        float v = vals[e];
        int bu = r >> BSH;
        int ru = atomicAdd(&h[bu], 1);
        sv[boff[bu] + bhpb[bu] + ru] = make_float2(__int_as_float(c | ((r & 255) << 20)), v);
        int sI = N_U + c;
        int bi = sI >> BSH;
        int ri = atomicAdd(&h[bi], 1);
        sv[boff[bi] + bhpb[bi] + ri] = make_float2(__int_as_float(r | ((sI & 255) << 20)), v);
    }
}

// phase 4: one block per bucket: exact CSR placement of its ~6.8K entries,
// emit per-segment cnt and end-offsets (random writes confined to ~55 KB window)
__global__ __launch_bounds__(256) void place2_kernel(const float2* __restrict__ sv,
                                                     const int* __restrict__ boff,
                                                     const int* __restrict__ bcnt,
                                                     int* __restrict__ off, int* __restrict__ cnt,
                                                     float2* __restrict__ edge) {
    int b = blockIdx.x;
    int start = boff[b], n = bcnt[b];
    __shared__ int h[256], hs[256], hc[256];
    h[threadIdx.x] = 0;
    hc[threadIdx.x] = 0;
    __syncthreads();
    for (int i = start + threadIdx.x; i < start + n; i += 256) {
        int packed = __float_as_int(sv[i].x);
        atomicAdd(&h[(packed >> 20) & 255], 1);
    }
    __syncthreads();
    if (threadIdx.x == 0) {
        int run = 0;
#pragma unroll
        for (int k = 0; k < 256; k++) { hs[k] = run; run += h[k]; }
    }
    __syncthreads();
    {
        int seg = b * 256 + threadIdx.x;
        if (seg < NSEG) {
            cnt[seg] = h[threadIdx.x];
            off[seg] = start + hs[threadIdx.x] + h[threadIdx.x];  // END offsets (spmm convention)
        }
    }
    for (int i = start + threadIdx.x; i < start + n; i += 256) {
        float2 p = sv[i];
        int packed = __float_as_int(p.x);
        int s = (packed >> 20) & 255;
        int r = atomicAdd(&hc[s], 1);
        edge[start + hs[s] + r] = make_float2(__int_as_float(packed & 0xFFFFF), p.y);
    }
}

// wave-per-row CSR SpMM; off[] holds END offsets, range = [end-cnt, end)
__global__ __launch_bounds__(256) void spmm_csr_kernel(
    const float2* __restrict__ edge, const int* __restrict__ off, const int* __restrict__ cnt,
    int base, const float* __restrict__ Esrc, float* __restrict__ out, float scale, int accum,
    int nrows) {
    int lane = threadIdx.x & 63;
    int row = (blockIdx.x * blockDim.x + threadIdx.x) >> 6;
    if (row >= nrows) return;
    int end = off[base + row];
    int n = cnt[base + row];
    int e = end - n;
    float acc = 0.f;
    for (; e + 4 <= end; e += 4) {
        float2 p0 = edge[e], p1 = edge[e + 1], p2 = edge[e + 2], p3 = edge[e + 3];
        float g0 = Esrc[(size_t)__float_as_int(p0.x) * 64 + lane];
        float g1 = Esrc[(size_t)__float_as_int(p1.x) * 64 + lane];
        float g2 = Esrc[(size_t)__float_as_int(p2.x) * 64 + lane];
        float g3 = Esrc[(size_t)__float_as_int(p3.x) * 64 + lane];
        acc = __builtin_fmaf(p0.y, g0, acc);
        acc = __builtin_fmaf(p1.y, g1, acc);
        acc = __builtin_fmaf(p2.y, g2, acc);
        acc = __builtin_fmaf(p3.y, g3, acc);
    }
    for (; e < end; e++) {
        float2 p = edge[e];
        acc = __builtin_fmaf(p.y, Esrc[(size_t)__float_as_int(p.x) * 64 + lane], acc);
    }
    size_t o = (size_t)row * 64 + lane;
    if (accum) out[o] += scale * acc;
    else out[o] = acc;
}

__global__ void rank_kernel(const float* __restrict__ X, const float* __restrict__ W,
                            float* __restrict__ P, int n) {
    int lane = threadIdx.x & 63;
    int wave = (blockIdx.x * blockDim.x + threadIdx.x) >> 6;
    int nw = (gridDim.x * blockDim.x) >> 6;
    float acc[RANK] = {0.f, 0.f, 0.f, 0.f, 0.f};
    for (int i = wave; i < n; i += nw) {
        float x = X[i * 64 + lane];
#pragma unroll
        for (int r = 0; r < RANK; r++) acc[r] = __builtin_fmaf(W[r * n + i], x, acc[r]);
    }
#pragma unroll
    for (int r = 0; r < RANK; r++) atomicAdd(&P[r * 64 + lane], acc[r]);
}

__global__ void pre_out_kernel(const float4* __restrict__ a, const float4* __restrict__ b,
                               float4* __restrict__ o, int n) {
    int i = blockIdx.x * blockDim.x + threadIdx.x;
    if (i < n) {
        float4 x = a[i], y = b[i];
        const float s = 1.f / 3.f;
        o[i] = make_float4((x.x + y.x) * s, (x.y + y.y) * s, (x.z + y.z) * s, (x.w + y.w) * s);
    }
}

__global__ void conv_bf16_kernel(const float* __restrict__ E, short* __restrict__ B, int n64,
                                 int npad64) {
    int i = blockIdx.x * blockDim.x + threadIdx.x;
    if (i < npad64) B[i] = (i < n64) ? f2bf(E[i]) : (short)0;
}

__global__ void gather_kernel(const int* __restrict__ ids, int m, const float* __restrict__ E0,
                              const float* __restrict__ PQ, const float* __restrict__ mulS,
                              const float* __restrict__ Eout, short* __restrict__ Gb,
                              float* __restrict__ acc, float coef) {
    int lane = threadIdx.x & 63;
    int k = (blockIdx.x * blockDim.x + threadIdx.x) >> 6;
    if (k >= m) return;
    int u = ids[k];
    float g = E0[u * 64 + lane];
#pragma unroll
    for (int r = 0; r < RANK; r++) g = __builtin_fmaf(mulS[u * RANK + r], PQ[r * 64 + lane], g);
    g *= (1.f / 3.f);
    Gb[k * 64 + lane] = f2bf(g);
    float d = g * Eout[u * 64 + lane];
#pragma unroll
    for (int off = 32; off; off >>= 1) d += __shfl_down(d, off);
    if (lane == 0) {
        float t = fminf(fmaxf(d * 5.f, -5.f), 5.f);
        atomicAdd(acc, coef * t);
    }
}

// M-register-blocked neg-GEMM: each wave holds A for all 64 block rows (4 groups),
// sweeps CPW columns; per B-load-pair we issue 8 MFMAs + 16 exp-accumulates.
// part layout: [row][nchunk] with nchunk = NCH*4 (each wave owns one chunk-column).
__global__ __launch_bounds__(256) void neg_mfma_kernel(const short* __restrict__ G16,
                                                       const short* __restrict__ E16,
                                                       float* __restrict__ part, int nchunk) {
    int lane = threadIdx.x & 63;
    int wave = threadIdx.x >> 6;
    int quad = lane >> 4;
    int rr = lane & 15;
    int rowbase = blockIdx.x * 64;
    short8 a0[4], a1[4];
#pragma unroll
    for (int g = 0; g < 4; g++) {
        const short8* ga = (const short8*)(G16 + (size_t)(rowbase + g * 16 + rr) * 64 + quad * 8);
        a0[g] = ga[0];
        a1[g] = ga[4];
    }
    int c0 = blockIdx.y * CPC + wave * CPW;
    float s[16];
#pragma unroll
    for (int i = 0; i < 16; i++) s[i] = 0.f;
    for (int ct = 0; ct < CPW; ct += 16) {
        const short8* eb = (const short8*)(E16 + (size_t)(c0 + ct + rr) * 64 + quad * 8);
        short8 b0 = eb[0];
        short8 b1 = eb[4];
#pragma unroll
        for (int g = 0; g < 4; g++) {
            floatx4 acc = {0.f, 0.f, 0.f, 0.f};
            acc = __builtin_amdgcn_mfma_f32_16x16x32_bf16(a0[g], b0, acc, 0, 0, 0);
            acc = __builtin_amdgcn_mfma_f32_16x16x32_bf16(a1[g], b1, acc, 0, 0, 0);
            s[g * 4 + 0] += __expf(acc[0] * 5.f);
            s[g * 4 + 1] += __expf(acc[1] * 5.f);
            s[g * 4 + 2] += __expf(acc[2] * 5.f);
            s[g * 4 + 3] += __expf(acc[3] * 5.f);
        }
    }
#pragma unroll
    for (int m = 8; m; m >>= 1) {
#pragma unroll
        for (int i = 0; i < 16; i++) s[i] += __shfl_xor(s[i], m);
    }
    if (rr == 0) {
        int col = blockIdx.y * 4 + wave;
#pragma unroll
        for (int g = 0; g < 4; g++) {
#pragma unroll
            for (int j = 0; j < 4; j++) {
                int row = rowbase + g * 16 + quad * 4 + j;
                part[(size_t)row * nchunk + col] = s[g * 4 + j];
            }
        }
    }
}

__global__ void combine_kernel(const float* __restrict__ part, int m, int nchunk, float pad,
                               float* __restrict__ acc, float coef) {
    int row = blockIdx.x * blockDim.x + threadIdx.x;
    if (row >= m) return;
    float S = 0.f;
    for (int c = 0; c < nchunk; c++) S += part[row * nchunk + c];
    float lse = __logf(S - pad);
    atomicAdd(acc, coef * lse);
}

__global__ void cat_kernel(const float* __restrict__ img, const float* __restrict__ txt,
                           float* __restrict__ out, int nrows) {
    int lane = threadIdx.x & 63;
    int row = (blockIdx.x * blockDim.x + threadIdx.x) >> 6;
    if (row >= nrows) return;
    float a = img[row * 64 + lane], b = txt[row * 64 + lane];
    float sa = a * a, sb = b * b;
#pragma unroll
    for (int msk = 32; msk; msk >>= 1) { sa += __shfl_xor(sa, msk); sb += __shfl_xor(sb, msk); }
    float ia = 1.f / fmaxf(sqrtf(sa), 1e-12f);
    float ib = 1.f / fmaxf(sqrtf(sb), 1e-12f);
    out[row * 64 + lane] += 0.02f * (a * ia + b * ib);
}

__global__ void loss_write_kernel(const float* __restrict__ acc, float* __restrict__ out) {
    out[0] = acc[0];
}

extern "C" void kernel_launch(void* const* d_in, const int* in_sizes, int n_in,
                              void* d_out, int out_size, void* d_ws, size_t ws_size,
                              hipStream_t stream) {
    const float* user_emb = (const float*)d_in[0];
    const float* item_emb = (const float*)d_in[1];
    const float* user_pre = (const float*)d_in[2];
    const float* item_pre = (const float*)d_in[3];
    const float* img_i = (const float*)d_in[4];
    const float* txt_i = (const float*)d_in[5];
    const float* img_u = (const float*)d_in[6];
    const float* txt_u = (const float*)d_in[7];
    const int* rows = (const int*)d_in[8];
    const int* cols = (const int*)d_in[9];
    const float* vals = (const float*)d_in[10];
    const float* ut = (const float*)d_in[11];
    const float* vt = (const float*)d_in[12];
    const float* u_mul_s = (const float*)d_in[13];
    const float* v_mul_s = (const float*)d_in[14];
    const int* uids = (const int*)d_in[15];
    const int* iids = (const int*)d_in[16];

    float* ws = (float*)d_ws;
    float* zu1 = ws + ZU1;
    float* zi1 = ws + ZI1;
    float2* edge = (float2*)(ws + EDGE);
    float* P = ws + P_OFF;
    float* Q = ws + Q_OFF;
    float* acc = ws + ACC_OFF;
    int* cnt = (int*)(ws + CNT_OFF);
    int* off = (int*)(ws + OFF_OFF);
    int* bcnt = (int*)(ws + BCNT_OFF);
    int* boff = (int*)(ws + BOFF_OFF);
    int* bsum = (int*)(ws + BSUM_OFF);
    float* eu0 = ws + EU0;
    float* ei0 = ws + EI0;
    float* part_u = ws + PART_U;
    float* part_i = ws + PART_I;
    int* bh = (int*)(ws + BH_OFF);
    int* bhp = (int*)(ws + BHP_OFF);
    float2* stage_sv = (float2*)(ws + STAGE_SV);
    short* ebu16 = (short*)(ws + EBU16);
    short* ebi16 = (short*)(ws + EBI16);
    short* gbu16 = (short*)(ws + GBU16);
    short* gbi16 = (short*)(ws + GBI16);

    float* out_u = (float*)d_out;
    float* out_i = out_u + (size_t)N_U * 64;
    float* out_loss = out_u + (size_t)(N_U + N_I) * 64;

    const int NB2 = (NBUCK + 255) / 256;  // 3 bucket-scan blocks

    // zero P,Q,acc only (cnt/off now written directly by place2)
    hipMemsetAsync(ws + P_OFF, 0, 704 * sizeof(float), stream);

    // ---- atomic-free CSR/CSC build ----
    bhist_kernel<<<NPB, 256, 0, stream>>>(rows, cols, bh);
    col_scan_kernel<<<NB2, 256, 0, stream>>>(bh, bhp, bcnt);
    scan1_kernel<<<NB2, 256, 0, stream>>>(bcnt, bsum, NBUCK);
    scan2_kernel<<<1, 1024, 0, stream>>>(bsum, NB2);
    scan3_kernel<<<NB2, 256, 0, stream>>>(bcnt, bsum, boff, NBUCK);
    bucket_place_kernel<<<NPB, 256, 0, stream>>>(rows, cols, vals, boff, bhp, stage_sv);
    place2_kernel<<<NBUCK, 256, 0, stream>>>(stage_sv, boff, bcnt, off, cnt, edge);

    // E0 = pre + emb
    ew_add_kernel<<<6250, 256, 0, stream>>>((const float4*)user_emb, (const float4*)user_pre,
                                            (float4*)eu0, 1600000);
    ew_add_kernel<<<3125, 256, 0, stream>>>((const float4*)item_emb, (const float4*)item_pre,
                                            (float4*)ei0, 800000);
    // layer-1 rank reductions
    rank_kernel<<<256, 256, 0, stream>>>(ei0, vt, P, N_I);
    rank_kernel<<<256, 256, 0, stream>>>(eu0, ut, Q, N_U);
    // layer-1 SpMM
    spmm_csr_kernel<<<N_U / 4, 256, 0, stream>>>(edge, off, cnt, 0, ei0, zu1, 1.f, 0, N_U);
    spmm_csr_kernel<<<N_I / 4, 256, 0, stream>>>(edge, off, cnt, N_U, eu0, zi1, 1.f, 0, N_I);
    // layer-2 rank reductions
    rank_kernel<<<256, 256, 0, stream>>>(zi1, vt, P, N_I);
    rank_kernel<<<256, 256, 0, stream>>>(zu1, ut, Q, N_U);
    // out = (E0 + Z1)/3, then layer-2 SpMM accumulates Z2/3 into out
    pre_out_kernel<<<6250, 256, 0, stream>>>((const float4*)eu0, (const float4*)zu1,
                                             (float4*)out_u, 1600000);
    pre_out_kernel<<<3125, 256, 0, stream>>>((const float4*)ei0, (const float4*)zi1,
                                             (float4*)out_i, 800000);
    spmm_csr_kernel<<<N_U / 4, 256, 0, stream>>>(edge, off, cnt, 0, zi1, out_u, 1.f / 3.f, 1,
                                                 N_U);
    spmm_csr_kernel<<<N_I / 4, 256, 0, stream>>>(edge, off, cnt, N_U, zu1, out_i, 1.f / 3.f, 1,
                                                 N_I);
    // bf16 copies of E (overlay in dead zu1 region; zero-padded tail rows)
    conv_bf16_kernel<<<(NPAD_U * 64 + 255) / 256, 256, 0, stream>>>(out_u, ebu16, N_U * 64,
                                                                   NPAD_U * 64);
    conv_bf16_kernel<<<(NPAD_I * 64 + 255) / 256, 256, 0, stream>>>(out_i, ebi16, N_I * 64,
                                                                   NPAD_I * 64);
    // sampled G rows (bf16) + pos term (fp32)
    gather_kernel<<<M_U / 4, 256, 0, stream>>>(uids, M_U, eu0, P, u_mul_s, out_u, gbu16, acc,
                                               -4.f / M_U);
    gather_kernel<<<M_I / 4, 256, 0, stream>>>(iids, M_I, ei0, Q, v_mul_s, out_i, gbi16, acc,
                                               -4.f / M_I);
    // neg term: MFMA exp-sum (4 chunk-columns per blockIdx.y: one per wave)
    dim3 gu(M_U / 64, NCH_U);
    neg_mfma_kernel<<<gu, 256, 0, stream>>>(gbu16, ebu16, part_u, NCH_U * 4);
    dim3 gi(M_I / 64, NCH_I);
    neg_mfma_kernel<<<gi, 256, 0, stream>>>(gbi16, ebi16, part_i, NCH_I * 4);
    combine_kernel<<<(M_U + 255) / 256, 256, 0, stream>>>(part_u, M_U, NCH_U * 4,
                                                          (float)(NPAD_U - N_U), acc, 4.f / M_U);
    combine_kernel<<<(M_I + 255) / 256, 256, 0, stream>>>(part_i, M_I, NCH_I * 4,
                                                          (float)(NPAD_I - N_I), acc, 4.f / M_I);
    // cat-rate terms (after loss consumed E from d_out)
    cat_kernel<<<(N_U * 64 + 255) / 256, 256, 0, stream>>>(img_u, txt_u, out_u, N_U);
    cat_kernel<<<(N_I * 64 + 255) / 256, 256, 0, stream>>>(img_i, txt_i, out_i, N_I);
    loss_write_kernel<<<1, 1, 0, stream>>>(acc, out_loss);
}

// Round 4
// 1119.049 us; speedup vs baseline: 1.4248x; 1.0418x over previous
//
#include <hip/hip_runtime.h>
#include <cstdint>

#define N_U 100000
#define N_I 50000
#define DIM 64
#define RANK 5
#define NNZ_ 2000000
#define M_U 2048
#define M_I 4096
#define NSEG 150000   // N_U + N_I combined segment count
#define BSH 8         // bucket = seg >> 8  (256 segments per bucket)
#define NBUCK 586     // ceil(NSEG/256)
#define NPB 512       // place blocks
#define CH 3907       // edges per place block (ceil(NNZ_/NPB))

// neg-GEMM tiling
#define CPC 3136
#define CPW 784       // CPC/4, columns per wave
#define NCH_U 32
#define NCH_I 16
#define NPAD_U (CPC * NCH_U)
#define NPAD_I (CPC * NCH_I)

typedef __attribute__((ext_vector_type(8))) short short8;
typedef __attribute__((ext_vector_type(4))) float floatx4;

// ---- workspace layout (float offsets) ----
static constexpr size_t ZU1 = 0;                       // 6.4M
static constexpr size_t ZI1 = 6400000;                 // 3.2M
static constexpr size_t EDGE = 9600000;                // 4M float2 = 8M floats
static constexpr size_t P_OFF = 17600000;              // 320
static constexpr size_t Q_OFF = 17600320;              // 320
static constexpr size_t ACC_OFF = 17600640;            // 1 (pad to 704)
static constexpr size_t CNT_OFF = 17600704;            // 150000 ints
static constexpr size_t OFF_OFF = 17750704;            // 150016 ints
static constexpr size_t BCNT_OFF = 17900720;           // NBUCK ints
static constexpr size_t BOFF_OFF = 17910144;           // NBUCK ints
static constexpr size_t BSUM_OFF = 17919552;           // 1024 ints
static constexpr size_t EU0 = 17920576;                // 6.4M
static constexpr size_t EI0 = EU0 + 6400000;           // 3.2M
static constexpr size_t PART_U = EI0 + 3200000;        // 2048*128 = 262144
static constexpr size_t PART_I = PART_U + (size_t)M_U * NCH_U * 4;  // 4096*64 = 262144
// end = PART_I + M_I*NCH_I*4 = 28,044,864 floats = 112.2 MB (< 115.7 MB cap)
// ---- staging overlays, live ONLY during CSR build (before spmm / before place2) ----
static constexpr size_t STAGE_SV = 0;                  // 4M float2 over ZU1+ZI1
static constexpr size_t BH_OFF = EDGE;                 // NPB*NBUCK ints, dead before place2
static constexpr size_t BHP_OFF = EDGE + (size_t)NPB * NBUCK;  // NPB*NBUCK ints
// BH+BHP = 2*512*586 = 600,064 floats < 8M edge region ✓
// ---- bf16 overlay inside ZU1 (zu1/zi1 dead after layer-2 spmm) ----
static constexpr size_t EBU16 = 0;                     // 3,211,264 fl
static constexpr size_t EBI16 = 3211264;               // 1,605,632 fl
static constexpr size_t GBU16 = EBI16 + 1605632;       // 65,536 fl
static constexpr size_t GBI16 = GBU16 + 65536;         // 131,072 fl -> end 5,013,504 < 6.4M

static __device__ __forceinline__ short f2bf(float x) {
    unsigned u = __builtin_bit_cast(unsigned, x);
    unsigned r = (u + 0x7fffu + ((u >> 16) & 1u)) >> 16;
    return (short)r;
}

static __device__ __forceinline__ float rdlane_f(int v, int l) {
    return __builtin_bit_cast(float, __builtin_amdgcn_readlane(v, l));
}

__global__ void ew_add_kernel(const float4* __restrict__ a, const float4* __restrict__ b,
                              float4* __restrict__ o, int n) {
    int i = blockIdx.x * blockDim.x + threadIdx.x;
    if (i < n) {
        float4 x = a[i], y = b[i];
        o[i] = make_float4(x.x + y.x, x.y + y.y, x.z + y.z, x.w + y.w);
    }
}

// ---------- atomic-free CSR/CSC build ----------
// phase 1: per-block LDS bucket histogram, dense writeout bh[block][bucket]
__global__ __launch_bounds__(256) void bhist_kernel(const int* __restrict__ rows,
                                                    const int* __restrict__ cols,
                                                    int* __restrict__ bh) {
    __shared__ int h[NBUCK];
    for (int i = threadIdx.x; i < NBUCK; i += 256) h[i] = 0;
    __syncthreads();
    int b = blockIdx.x;
    int lo = b * CH, hi = min(lo + CH, NNZ_);
    for (int e = lo + threadIdx.x; e < hi; e += 256) {
        atomicAdd(&h[rows[e] >> BSH], 1);
        atomicAdd(&h[(N_U + cols[e]) >> BSH], 1);
    }
    __syncthreads();
    for (int i = threadIdx.x; i < NBUCK; i += 256) bh[(size_t)b * NBUCK + i] = h[i];
}

// phase 2: coalesced column scan: one thread per bucket, serial over NPB blocks.
__global__ __launch_bounds__(256) void col_scan_kernel(const int* __restrict__ bh,
                                                       int* __restrict__ bhp,
                                                       int* __restrict__ bcnt) {
    int j = blockIdx.x * 256 + threadIdx.x;
    if (j >= NBUCK) return;
    int run = 0;
#pragma unroll 16
    for (int b = 0; b < NPB; b++) {
        int v = bh[(size_t)b * NBUCK + j];
        bhp[(size_t)b * NBUCK + j] = run;
        run += v;
    }
    bcnt[j] = run;
}

__global__ void scan1_kernel(const int* __restrict__ cnt, int* __restrict__ bsum, int n) {
    int i = blockIdx.x * 256 + threadIdx.x;
    int v = (i < n) ? cnt[i] : 0;
#pragma unroll
    for (int off = 32; off; off >>= 1) v += __shfl_down(v, off);
    __shared__ int ls[4];
    int lane = threadIdx.x & 63, w = threadIdx.x >> 6;
    if (lane == 0) ls[w] = v;
    __syncthreads();
    if (threadIdx.x == 0) bsum[blockIdx.x] = ls[0] + ls[1] + ls[2] + ls[3];
}

__global__ void scan2_kernel(int* __restrict__ bsum, int nb) {
    __shared__ int s[1024];
    int t = threadIdx.x;
    s[t] = (t < nb) ? bsum[t] : 0;
    __syncthreads();
    for (int off = 1; off < 1024; off <<= 1) {
        int v = (t >= off) ? s[t - off] : 0;
        __syncthreads();
        s[t] += v;
        __syncthreads();
    }
    if (t < nb) bsum[t] = (t == 0) ? 0 : s[t - 1];
}

__global__ void scan3_kernel(const int* __restrict__ cnt, const int* __restrict__ bsum,
                             int* __restrict__ off, int n) {
    __shared__ int s[256];
    int i = blockIdx.x * 256 + threadIdx.x;
    int t = threadIdx.x;
    int c = (i < n) ? cnt[i] : 0;
    s[t] = c;
    __syncthreads();
    for (int o = 1; o < 256; o <<= 1) {
        int v = (t >= o) ? s[t - o] : 0;
        __syncthreads();
        s[t] += v;
        __syncthreads();
    }
    if (i < n) off[i] = bsum[blockIdx.x] + s[t] - c;
}

// phase 3: deterministic placement into bucket-grouped staging (no global atomics).
// entry = (idx | (seg&255)<<20, val) -- idx < 2^20, 8-bit tag recovers segment in place2.
__global__ __launch_bounds__(256) void bucket_place_kernel(
    const int* __restrict__ rows, const int* __restrict__ cols, const float* __restrict__ vals,
    const int* __restrict__ boff, const int* __restrict__ bhp, float2* __restrict__ sv) {
    __shared__ int h[NBUCK];
    for (int i = threadIdx.x; i < NBUCK; i += 256) h[i] = 0;
    __syncthreads();
    int b = blockIdx.x;
    int lo = b * CH, hi = min(lo + CH, NNZ_);
    const int* bhpb = bhp + (size_t)b * NBUCK;
    for (int e = lo + threadIdx.x; e < hi; e += 256) {
        int r = rows[e], c = cols[e];
        float v = vals[e];
        int bu = r >> BSH;
        int ru = atomicAdd(&h[bu], 1);
        sv[boff[bu] + bhpb[bu] + ru] = make_float2(__int_as_float(c | ((r & 255) << 20)), v);
        int sI = N_U + c;
        int bi = sI >> BSH;
        int ri = atomicAdd(&h[bi], 1);
        sv[boff[bi] + bhpb[bi] + ri] = make_float2(__int_as_float(r | ((sI & 255) << 20)), v);
    }
}

// phase 4: one block per bucket: exact CSR placement of its ~6.8K entries
__global__ __launch_bounds__(256) void place2_kernel(const float2* __restrict__ sv,
                                                     const int* __restrict__ boff,
                                                     const int* __restrict__ bcnt,
                                                     int* __restrict__ off, int* __restrict__ cnt,
                                                     float2* __restrict__ edge) {
    int b = blockIdx.x;
    int start = boff[b], n = bcnt[b];
    __shared__ int h[256], hs[256], hc[256];
    h[threadIdx.x] = 0;
    hc[threadIdx.x] = 0;
    __syncthreads();
    for (int i = start + threadIdx.x; i < start + n; i += 256) {
        int packed = __float_as_int(sv[i].x);
        atomicAdd(&h[(packed >> 20) & 255], 1);
    }
    __syncthreads();
    if (threadIdx.x == 0) {
        int run = 0;
#pragma unroll
        for (int k = 0; k < 256; k++) { hs[k] = run; run += h[k]; }
    }
    __syncthreads();
    {
        int seg = b * 256 + threadIdx.x;
        if (seg < NSEG) {
            cnt[seg] = h[threadIdx.x];
            off[seg] = start + hs[threadIdx.x] + h[threadIdx.x];  // END offsets (spmm convention)
        }
    }
    for (int i = start + threadIdx.x; i < start + n; i += 256) {
        float2 p = sv[i];
        int packed = __float_as_int(p.x);
        int s = (packed >> 20) & 255;
        int r = atomicAdd(&hc[s], 1);
        edge[start + hs[s] + r] = make_float2(__int_as_float(packed & 0xFFFFF), p.y);
    }
}

// wave-per-row CSR SpMM; off[] holds END offsets, range = [end-cnt, end).
// Cooperative: wave loads <=64 edges in ONE coalesced 512B read (one per lane),
// then broadcasts idx/val via readlane (SALU) and issues 8 independent gathers
// per round -> ~1 edge round-trip + ceil(n/8) gather round-trips per row.
__global__ __launch_bounds__(256) void spmm_csr_kernel(
    const float2* __restrict__ edge, const int* __restrict__ off, const int* __restrict__ cnt,
    int base, const float* __restrict__ Esrc, float* __restrict__ out, float scale, int accum,
    int nrows) {
    int lane = threadIdx.x & 63;
    int row = (blockIdx.x * blockDim.x + threadIdx.x) >> 6;
    if (row >= nrows) return;
    int end = off[base + row];
    int n = cnt[base + row];
    int e = end - n;
    float acc = 0.f;
    while (e < end) {
        int m = min(64, end - e);
        float2 p = (lane < m) ? edge[e + lane] : make_float2(0.f, 0.f);
        int vidx = __float_as_int(p.x);
        int vval = __float_as_int(p.y);
        int j = 0;
        for (; j + 8 <= m; j += 8) {
            int i0 = __builtin_amdgcn_readlane(vidx, j + 0);
            int i1 = __builtin_amdgcn_readlane(vidx, j + 1);
            int i2 = __builtin_amdgcn_readlane(vidx, j + 2);
            int i3 = __builtin_amdgcn_readlane(vidx, j + 3);
            int i4 = __builtin_amdgcn_readlane(vidx, j + 4);
            int i5 = __builtin_amdgcn_readlane(vidx, j + 5);
            int i6 = __builtin_amdgcn_readlane(vidx, j + 6);
            int i7 = __builtin_amdgcn_readlane(vidx, j + 7);
            float g0 = Esrc[(size_t)i0 * 64 + lane];
            float g1 = Esrc[(size_t)i1 * 64 + lane];
            float g2 = Esrc[(size_t)i2 * 64 + lane];
            float g3 = Esrc[(size_t)i3 * 64 + lane];
            float g4 = Esrc[(size_t)i4 * 64 + lane];
            float g5 = Esrc[(size_t)i5 * 64 + lane];
            float g6 = Esrc[(size_t)i6 * 64 + lane];
            float g7 = Esrc[(size_t)i7 * 64 + lane];
            acc = __builtin_fmaf(rdlane_f(vval, j + 0), g0, acc);
            acc = __builtin_fmaf(rdlane_f(vval, j + 1), g1, acc);
            acc = __builtin_fmaf(rdlane_f(vval, j + 2), g2, acc);
            acc = __builtin_fmaf(rdlane_f(vval, j + 3), g3, acc);
            acc = __builtin_fmaf(rdlane_f(vval, j + 4), g4, acc);
            acc = __builtin_fmaf(rdlane_f(vval, j + 5), g5, acc);
            acc = __builtin_fmaf(rdlane_f(vval, j + 6), g6, acc);
            acc = __builtin_fmaf(rdlane_f(vval, j + 7), g7, acc);
        }
        for (; j < m; j++) {
            int i0 = __builtin_amdgcn_readlane(vidx, j);
            acc = __builtin_fmaf(rdlane_f(vval, j), Esrc[(size_t)i0 * 64 + lane], acc);
        }
        e += m;
    }
    size_t o = (size_t)row * 64 + lane;
    if (accum) out[o] += scale * acc;
    else out[o] = acc;
}

__global__ void rank_kernel(const float* __restrict__ X, const float* __restrict__ W,
                            float* __restrict__ P, int n) {
    int lane = threadIdx.x & 63;
    int wave = (blockIdx.x * blockDim.x + threadIdx.x) >> 6;
    int nw = (gridDim.x * blockDim.x) >> 6;
    float acc[RANK] = {0.f, 0.f, 0.f, 0.f, 0.f};
    for (int i = wave; i < n; i += nw) {
        float x = X[i * 64 + lane];
#pragma unroll
        for (int r = 0; r < RANK; r++) acc[r] = __builtin_fmaf(W[r * n + i], x, acc[r]);
    }
#pragma unroll
    for (int r = 0; r < RANK; r++) atomicAdd(&P[r * 64 + lane], acc[r]);
}

__global__ void pre_out_kernel(const float4* __restrict__ a, const float4* __restrict__ b,
                               float4* __restrict__ o, int n) {
    int i = blockIdx.x * blockDim.x + threadIdx.x;
    if (i < n) {
        float4 x = a[i], y = b[i];
        const float s = 1.f / 3.f;
        o[i] = make_float4((x.x + y.x) * s, (x.y + y.y) * s, (x.z + y.z) * s, (x.w + y.w) * s);
    }
}

__global__ void conv_bf16_kernel(const float* __restrict__ E, short* __restrict__ B, int n64,
                                 int npad64) {
    int i = blockIdx.x * blockDim.x + threadIdx.x;
    if (i < npad64) B[i] = (i < n64) ? f2bf(E[i]) : (short)0;
}

__global__ void gather_kernel(const int* __restrict__ ids, int m, const float* __restrict__ E0,
                              const float* __restrict__ PQ, const float* __restrict__ mulS,
                              const float* __restrict__ Eout, short* __restrict__ Gb,
                              float* __restrict__ acc, float coef) {
    int lane = threadIdx.x & 63;
    int k = (blockIdx.x * blockDim.x + threadIdx.x) >> 6;
    if (k >= m) return;
    int u = ids[k];
    float g = E0[u * 64 + lane];
#pragma unroll
    for (int r = 0; r < RANK; r++) g = __builtin_fmaf(mulS[u * RANK + r], PQ[r * 64 + lane], g);
    g *= (1.f / 3.f);
    Gb[k * 64 + lane] = f2bf(g);
    float d = g * Eout[u * 64 + lane];
#pragma unroll
    for (int off = 32; off; off >>= 1) d += __shfl_down(d, off);
    if (lane == 0) {
        float t = fminf(fmaxf(d * 5.f, -5.f), 5.f);
        atomicAdd(acc, coef * t);
    }
}

// M-register-blocked neg-GEMM: each wave holds A for all 64 block rows (4 groups),
// sweeps CPW columns; per B-load-pair we issue 8 MFMAs + 16 exp-accumulates.
__global__ __launch_bounds__(256) void neg_mfma_kernel(const short* __restrict__ G16,
                                                       const short* __restrict__ E16,
                                                       float* __restrict__ part, int nchunk) {
    int lane = threadIdx.x & 63;
    int wave = threadIdx.x >> 6;
    int quad = lane >> 4;
    int rr = lane & 15;
    int rowbase = blockIdx.x * 64;
    short8 a0[4], a1[4];
#pragma unroll
    for (int g = 0; g < 4; g++) {
        const short8* ga = (const short8*)(G16 + (size_t)(rowbase + g * 16 + rr) * 64 + quad * 8);
        a0[g] = ga[0];
        a1[g] = ga[4];
    }
    int c0 = blockIdx.y * CPC + wave * CPW;
    float s[16];
#pragma unroll
    for (int i = 0; i < 16; i++) s[i] = 0.f;
    for (int ct = 0; ct < CPW; ct += 16) {
        const short8* eb = (const short8*)(E16 + (size_t)(c0 + ct + rr) * 64 + quad * 8);
        short8 b0 = eb[0];
        short8 b1 = eb[4];
#pragma unroll
        for (int g = 0; g < 4; g++) {
            floatx4 acc = {0.f, 0.f, 0.f, 0.f};
            acc = __builtin_amdgcn_mfma_f32_16x16x32_bf16(a0[g], b0, acc, 0, 0, 0);
            acc = __builtin_amdgcn_mfma_f32_16x16x32_bf16(a1[g], b1, acc, 0, 0, 0);
            s[g * 4 + 0] += __expf(acc[0] * 5.f);
            s[g * 4 + 1] += __expf(acc[1] * 5.f);
            s[g * 4 + 2] += __expf(acc[2] * 5.f);
            s[g * 4 + 3] += __expf(acc[3] * 5.f);
        }
    }
#pragma unroll
    for (int m = 8; m; m >>= 1) {
#pragma unroll
        for (int i = 0; i < 16; i++) s[i] += __shfl_xor(s[i], m);
    }
    if (rr == 0) {
        int col = blockIdx.y * 4 + wave;
#pragma unroll
        for (int g = 0; g < 4; g++) {
#pragma unroll
            for (int j = 0; j < 4; j++) {
                int row = rowbase + g * 16 + quad * 4 + j;
                part[(size_t)row * nchunk + col] = s[g * 4 + j];
            }
        }
    }
}

__global__ void combine_kernel(const float* __restrict__ part, int m, int nchunk, float pad,
                               float* __restrict__ acc, float coef) {
    int row = blockIdx.x * blockDim.x + threadIdx.x;
    if (row >= m) return;
    float S = 0.f;
    for (int c = 0; c < nchunk; c++) S += part[row * nchunk + c];
    float lse = __logf(S - pad);
    atomicAdd(acc, coef * lse);
}

__global__ void cat_kernel(const float* __restrict__ img, const float* __restrict__ txt,
                           float* __restrict__ out, int nrows) {
    int lane = threadIdx.x & 63;
    int row = (blockIdx.x * blockDim.x + threadIdx.x) >> 6;
    if (row >= nrows) return;
    float a = img[row * 64 + lane], b = txt[row * 64 + lane];
    float sa = a * a, sb = b * b;
#pragma unroll
    for (int msk = 32; msk; msk >>= 1) { sa += __shfl_xor(sa, msk); sb += __shfl_xor(sb, msk); }
    float ia = 1.f / fmaxf(sqrtf(sa), 1e-12f);
    float ib = 1.f / fmaxf(sqrtf(sb), 1e-12f);
    out[row * 64 + lane] += 0.02f * (a * ia + b * ib);
}

__global__ void loss_write_kernel(const float* __restrict__ acc, float* __restrict__ out) {
    out[0] = acc[0];
}

extern "C" void kernel_launch(void* const* d_in, const int* in_sizes, int n_in,
                              void* d_out, int out_size, void* d_ws, size_t ws_size,
                              hipStream_t stream) {
    const float* user_emb = (const float*)d_in[0];
    const float* item_emb = (const float*)d_in[1];
    const float* user_pre = (const float*)d_in[2];
    const float* item_pre = (const float*)d_in[3];
    const float* img_i = (const float*)d_in[4];
    const float* txt_i = (const float*)d_in[5];
    const float* img_u = (const float*)d_in[6];
    const float* txt_u = (const float*)d_in[7];
    const int* rows = (const int*)d_in[8];
    const int* cols = (const int*)d_in[9];
    const float* vals = (const float*)d_in[10];
    const float* ut = (const float*)d_in[11];
    const float* vt = (const float*)d_in[12];
    const float* u_mul_s = (const float*)d_in[13];
    const float* v_mul_s = (const float*)d_in[14];
    const int* uids = (const int*)d_in[15];
    const int* iids = (const int*)d_in[16];

    float* ws = (float*)d_ws;
    float* zu1 = ws + ZU1;
    float* zi1 = ws + ZI1;
    float2* edge = (float2*)(ws + EDGE);
    float* P = ws + P_OFF;
    float* Q = ws + Q_OFF;
    float* acc = ws + ACC_OFF;
    int* cnt = (int*)(ws + CNT_OFF);
    int* off = (int*)(ws + OFF_OFF);
    int* bcnt = (int*)(ws + BCNT_OFF);
    int* boff = (int*)(ws + BOFF_OFF);
    int* bsum = (int*)(ws + BSUM_OFF);
    float* eu0 = ws + EU0;
    float* ei0 = ws + EI0;
    float* part_u = ws + PART_U;
    float* part_i = ws + PART_I;
    int* bh = (int*)(ws + BH_OFF);
    int* bhp = (int*)(ws + BHP_OFF);
    float2* stage_sv = (float2*)(ws + STAGE_SV);
    short* ebu16 = (short*)(ws + EBU16);
    short* ebi16 = (short*)(ws + EBI16);
    short* gbu16 = (short*)(ws + GBU16);
    short* gbi16 = (short*)(ws + GBI16);

    float* out_u = (float*)d_out;
    float* out_i = out_u + (size_t)N_U * 64;
    float* out_loss = out_u + (size_t)(N_U + N_I) * 64;

    const int NB2 = (NBUCK + 255) / 256;  // 3 bucket-scan blocks

    // zero P,Q,acc only (cnt/off now written directly by place2)
    hipMemsetAsync(ws + P_OFF, 0, 704 * sizeof(float), stream);

    // ---- atomic-free CSR/CSC build ----
    bhist_kernel<<<NPB, 256, 0, stream>>>(rows, cols, bh);
    col_scan_kernel<<<NB2, 256, 0, stream>>>(bh, bhp, bcnt);
    scan1_kernel<<<NB2, 256, 0, stream>>>(bcnt, bsum, NBUCK);
    scan2_kernel<<<1, 1024, 0, stream>>>(bsum, NB2);
    scan3_kernel<<<NB2, 256, 0, stream>>>(bcnt, bsum, boff, NBUCK);
    bucket_place_kernel<<<NPB, 256, 0, stream>>>(rows, cols, vals, boff, bhp, stage_sv);
    place2_kernel<<<NBUCK, 256, 0, stream>>>(stage_sv, boff, bcnt, off, cnt, edge);

    // E0 = pre + emb
    ew_add_kernel<<<6250, 256, 0, stream>>>((const float4*)user_emb, (const float4*)user_pre,
                                            (float4*)eu0, 1600000);
    ew_add_kernel<<<3125, 256, 0, stream>>>((const float4*)item_emb, (const float4*)item_pre,
                                            (float4*)ei0, 800000);
    // layer-1 rank reductions
    rank_kernel<<<256, 256, 0, stream>>>(ei0, vt, P, N_I);
    rank_kernel<<<256, 256, 0, stream>>>(eu0, ut, Q, N_U);
    // layer-1 SpMM
    spmm_csr_kernel<<<N_U / 4, 256, 0, stream>>>(edge, off, cnt, 0, ei0, zu1, 1.f, 0, N_U);
    spmm_csr_kernel<<<N_I / 4, 256, 0, stream>>>(edge, off, cnt, N_U, eu0, zi1, 1.f, 0, N_I);
    // layer-2 rank reductions
    rank_kernel<<<256, 256, 0, stream>>>(zi1, vt, P, N_I);
    rank_kernel<<<256, 256, 0, stream>>>(zu1, ut, Q, N_U);
    // out = (E0 + Z1)/3, then layer-2 SpMM accumulates Z2/3 into out
    pre_out_kernel<<<6250, 256, 0, stream>>>((const float4*)eu0, (const float4*)zu1,
                                             (float4*)out_u, 1600000);
    pre_out_kernel<<<3125, 256, 0, stream>>>((const float4*)ei0, (const float4*)zi1,
                                             (float4*)out_i, 800000);
    spmm_csr_kernel<<<N_U / 4, 256, 0, stream>>>(edge, off, cnt, 0, zi1, out_u, 1.f / 3.f, 1,
                                                 N_U);
    spmm_csr_kernel<<<N_I / 4, 256, 0, stream>>>(edge, off, cnt, N_U, zu1, out_i, 1.f / 3.f, 1,
                                                 N_I);
    // bf16 copies of E (overlay in dead zu1 region; zero-padded tail rows)
    conv_bf16_kernel<<<(NPAD_U * 64 + 255) / 256, 256, 0, stream>>>(out_u, ebu16, N_U * 64,
                                                                   NPAD_U * 64);
    conv_bf16_kernel<<<(NPAD_I * 64 + 255) / 256, 256, 0, stream>>>(out_i, ebi16, N_I * 64,
                                                                   NPAD_I * 64);
    // sampled G rows (bf16) + pos term (fp32)
    gather_kernel<<<M_U / 4, 256, 0, stream>>>(uids, M_U, eu0, P, u_mul_s, out_u, gbu16, acc,
                                               -4.f / M_U);
    gather_kernel<<<M_I / 4, 256, 0, stream>>>(iids, M_I, ei0, Q, v_mul_s, out_i, gbi16, acc,
                                               -4.f / M_I);
    // neg term: MFMA exp-sum (4 chunk-columns per blockIdx.y: one per wave)
    dim3 gu(M_U / 64, NCH_U);
    neg_mfma_kernel<<<gu, 256, 0, stream>>>(gbu16, ebu16, part_u, NCH_U * 4);
    dim3 gi(M_I / 64, NCH_I);
    neg_mfma_kernel<<<gi, 256, 0, stream>>>(gbi16, ebi16, part_i, NCH_I * 4);
    combine_kernel<<<(M_U + 255) / 256, 256, 0, stream>>>(part_u, M_U, NCH_U * 4,
                                                          (float)(NPAD_U - N_U), acc, 4.f / M_U);
    combine_kernel<<<(M_I + 255) / 256, 256, 0, stream>>>(part_i, M_I, NCH_I * 4,
                                                          (float)(NPAD_I - N_I), acc, 4.f / M_I);
    // cat-rate terms (after loss consumed E from d_out)
    cat_kernel<<<(N_U * 64 + 255) / 256, 256, 0, stream>>>(img_u, txt_u, out_u, N_U);
    cat_kernel<<<(N_I * 64 + 255) / 256, 256, 0, stream>>>(img_i, txt_i, out_i, N_I);
    loss_write_kernel<<<1, 1, 0, stream>>>(acc, out_loss);
}

// Round 5
// 1020.056 us; speedup vs baseline: 1.5631x; 1.0970x over previous
//
#include <hip/hip_runtime.h>
#include <cstdint>

#define N_U 100000
#define N_I 50000
#define DIM 64
#define RANK 5
#define NNZ_ 2000000
#define M_U 2048
#define M_I 4096
#define NSEG 150000   // N_U + N_I combined segment count
#define BSH 8         // bucket = seg >> 8  (256 segments per bucket)
#define NBUCK 586     // ceil(NSEG/256)
#define NPB 512       // place blocks
#define CH 3907       // edges per place block (ceil(NNZ_/NPB))

// neg-GEMM tiling
#define CPC 3136
#define CPW 784       // CPC/4, columns per wave
#define NCH_U 32
#define NCH_I 16
#define NPAD_U (CPC * NCH_U)
#define NPAD_I (CPC * NCH_I)

typedef __attribute__((ext_vector_type(8))) short short8;
typedef __attribute__((ext_vector_type(4))) float floatx4;

// ---- workspace layout (float offsets) ----
static constexpr size_t ZU1 = 0;                       // 6.4M
static constexpr size_t ZI1 = 6400000;                 // 3.2M
static constexpr size_t EDGE = 9600000;                // 4M float2 = 8M floats
static constexpr size_t P_OFF = 17600000;              // 320
static constexpr size_t Q_OFF = 17600320;              // 320
static constexpr size_t ACC_OFF = 17600640;            // 1 (pad to 704)
static constexpr size_t CNT_OFF = 17600704;            // 150000 ints
static constexpr size_t OFF_OFF = 17750704;            // 150016 ints
static constexpr size_t BCNT_OFF = 17900720;           // NBUCK ints
static constexpr size_t BOFF_OFF = 17910144;           // NBUCK ints
static constexpr size_t BSUM_OFF = 17919552;           // 1024 ints
static constexpr size_t EU0 = 17920576;                // 6.4M
static constexpr size_t EI0 = EU0 + 6400000;           // 3.2M
static constexpr size_t PART_U = EI0 + 3200000;        // 2048*128 = 262144
static constexpr size_t PART_I = PART_U + (size_t)M_U * NCH_U * 4;  // 4096*64 = 262144
// end = PART_I + M_I*NCH_I*4 = 28,044,864 floats = 112.2 MB (< 115.7 MB cap)
// ---- staging overlays, live ONLY during CSR build (before spmm / before place2) ----
static constexpr size_t STAGE_SV = 0;                  // 4M float2 over ZU1+ZI1
static constexpr size_t BH_OFF = EDGE;                 // NPB*NBUCK ints, dead before place2
static constexpr size_t BHP_OFF = EDGE + (size_t)NPB * NBUCK;  // NPB*NBUCK ints
// BH+BHP = 2*512*586 = 600,064 floats < 8M edge region ✓
// ---- bf16 overlay inside ZU1 (zu1/zi1 dead after layer-2 spmm) ----
static constexpr size_t EBU16 = 0;                     // 3,211,264 fl
static constexpr size_t EBI16 = 3211264;               // 1,605,632 fl
static constexpr size_t GBU16 = EBI16 + 1605632;       // 65,536 fl
static constexpr size_t GBI16 = GBU16 + 65536;         // 131,072 fl -> end 5,013,504 < 6.4M

static __device__ __forceinline__ short f2bf(float x) {
    unsigned u = __builtin_bit_cast(unsigned, x);
    unsigned r = (u + 0x7fffu + ((u >> 16) & 1u)) >> 16;
    return (short)r;
}

static __device__ __forceinline__ float rdlane_f(int v, int l) {
    return __builtin_bit_cast(float, __builtin_amdgcn_readlane(v, l));
}

__global__ void ew_add_kernel(const float4* __restrict__ a, const float4* __restrict__ b,
                              float4* __restrict__ o, int n) {
    int i = blockIdx.x * blockDim.x + threadIdx.x;
    if (i < n) {
        float4 x = a[i], y = b[i];
        o[i] = make_float4(x.x + y.x, x.y + y.y, x.z + y.z, x.w + y.w);
    }
}

// ---------- atomic-free CSR/CSC build ----------
// phase 1: per-block LDS bucket histogram, dense writeout bh[block][bucket]
__global__ __launch_bounds__(256) void bhist_kernel(const int* __restrict__ rows,
                                                    const int* __restrict__ cols,
                                                    int* __restrict__ bh) {
    __shared__ int h[NBUCK];
    for (int i = threadIdx.x; i < NBUCK; i += 256) h[i] = 0;
    __syncthreads();
    int b = blockIdx.x;
    int lo = b * CH, hi = min(lo + CH, NNZ_);
    for (int e = lo + threadIdx.x; e < hi; e += 256) {
        atomicAdd(&h[rows[e] >> BSH], 1);
        atomicAdd(&h[(N_U + cols[e]) >> BSH], 1);
    }
    __syncthreads();
    for (int i = threadIdx.x; i < NBUCK; i += 256) bh[(size_t)b * NBUCK + i] = h[i];
}

// phase 2: coalesced column scan: one thread per bucket, serial over NPB blocks.
__global__ __launch_bounds__(256) void col_scan_kernel(const int* __restrict__ bh,
                                                       int* __restrict__ bhp,
                                                       int* __restrict__ bcnt) {
    int j = blockIdx.x * 256 + threadIdx.x;
    if (j >= NBUCK) return;
    int run = 0;
#pragma unroll 16
    for (int b = 0; b < NPB; b++) {
        int v = bh[(size_t)b * NBUCK + j];
        bhp[(size_t)b * NBUCK + j] = run;
        run += v;
    }
    bcnt[j] = run;
}

__global__ void scan1_kernel(const int* __restrict__ cnt, int* __restrict__ bsum, int n) {
    int i = blockIdx.x * 256 + threadIdx.x;
    int v = (i < n) ? cnt[i] : 0;
#pragma unroll
    for (int off = 32; off; off >>= 1) v += __shfl_down(v, off);
    __shared__ int ls[4];
    int lane = threadIdx.x & 63, w = threadIdx.x >> 6;
    if (lane == 0) ls[w] = v;
    __syncthreads();
    if (threadIdx.x == 0) bsum[blockIdx.x] = ls[0] + ls[1] + ls[2] + ls[3];
}

__global__ void scan2_kernel(int* __restrict__ bsum, int nb) {
    __shared__ int s[1024];
    int t = threadIdx.x;
    s[t] = (t < nb) ? bsum[t] : 0;
    __syncthreads();
    for (int off = 1; off < 1024; off <<= 1) {
        int v = (t >= off) ? s[t - off] : 0;
        __syncthreads();
        s[t] += v;
        __syncthreads();
    }
    if (t < nb) bsum[t] = (t == 0) ? 0 : s[t - 1];
}

__global__ void scan3_kernel(const int* __restrict__ cnt, const int* __restrict__ bsum,
                             int* __restrict__ off, int n) {
    __shared__ int s[256];
    int i = blockIdx.x * 256 + threadIdx.x;
    int t = threadIdx.x;
    int c = (i < n) ? cnt[i] : 0;
    s[t] = c;
    __syncthreads();
    for (int o = 1; o < 256; o <<= 1) {
        int v = (t >= o) ? s[t - o] : 0;
        __syncthreads();
        s[t] += v;
        __syncthreads();
    }
    if (i < n) off[i] = bsum[blockIdx.x] + s[t] - c;
}

// phase 3: deterministic placement into bucket-grouped staging (no global atomics).
// entry = (idx | (seg&255)<<20, val) -- idx < 2^20, 8-bit tag recovers segment in place2.
__global__ __launch_bounds__(256) void bucket_place_kernel(
    const int* __restrict__ rows, const int* __restrict__ cols, const float* __restrict__ vals,
    const int* __restrict__ boff, const int* __restrict__ bhp, float2* __restrict__ sv) {
    __shared__ int h[NBUCK];
    for (int i = threadIdx.x; i < NBUCK; i += 256) h[i] = 0;
    __syncthreads();
    int b = blockIdx.x;
    int lo = b * CH, hi = min(lo + CH, NNZ_);
    const int* bhpb = bhp + (size_t)b * NBUCK;
    for (int e = lo + threadIdx.x; e < hi; e += 256) {
        int r = rows[e], c = cols[e];
        float v = vals[e];
        int bu = r >> BSH;
        int ru = atomicAdd(&h[bu], 1);
        sv[boff[bu] + bhpb[bu] + ru] = make_float2(__int_as_float(c | ((r & 255) << 20)), v);
        int sI = N_U + c;
        int bi = sI >> BSH;
        int ri = atomicAdd(&h[bi], 1);
        sv[boff[bi] + bhpb[bi] + ri] = make_float2(__int_as_float(r | ((sI & 255) << 20)), v);
    }
}

// phase 4: one block per bucket: exact CSR placement of its ~6.8K entries
__global__ __launch_bounds__(256) void place2_kernel(const float2* __restrict__ sv,
                                                     const int* __restrict__ boff,
                                                     const int* __restrict__ bcnt,
                                                     int* __restrict__ off, int* __restrict__ cnt,
                                                     float2* __restrict__ edge) {
    int b = blockIdx.x;
    int start = boff[b], n = bcnt[b];
    __shared__ int h[256], hs[256], hc[256];
    h[threadIdx.x] = 0;
    hc[threadIdx.x] = 0;
    __syncthreads();
    for (int i = start + threadIdx.x; i < start + n; i += 256) {
        int packed = __float_as_int(sv[i].x);
        atomicAdd(&h[(packed >> 20) & 255], 1);
    }
    __syncthreads();
    if (threadIdx.x == 0) {
        int run = 0;
#pragma unroll
        for (int k = 0; k < 256; k++) { hs[k] = run; run += h[k]; }
    }
    __syncthreads();
    {
        int seg = b * 256 + threadIdx.x;
        if (seg < NSEG) {
            cnt[seg] = h[threadIdx.x];
            off[seg] = start + hs[threadIdx.x] + h[threadIdx.x];  // END offsets (spmm convention)
        }
    }
    for (int i = start + threadIdx.x; i < start + n; i += 256) {
        float2 p = sv[i];
        int packed = __float_as_int(p.x);
        int s = (packed >> 20) & 255;
        int r = atomicAdd(&hc[s], 1);
        edge[start + hs[s] + r] = make_float2(__int_as_float(packed & 0xFFFFF), p.y);
    }
}

// wave-per-row CSR SpMM; off[] holds END offsets, range = [end-cnt, end).
// Cooperative: wave loads <=64 edges in ONE coalesced 512B read (one per lane),
// then broadcasts idx/val via readlane (SALU) and issues 8 independent gathers
// per round -> ~1 edge round-trip + ceil(n/8) gather round-trips per row.
__global__ __launch_bounds__(256) void spmm_csr_kernel(
    const float2* __restrict__ edge, const int* __restrict__ off, const int* __restrict__ cnt,
    int base, const float* __restrict__ Esrc, float* __restrict__ out, float scale, int accum,
    int nrows) {
    int lane = threadIdx.x & 63;
    int row = (blockIdx.x * blockDim.x + threadIdx.x) >> 6;
    if (row >= nrows) return;
    int end = off[base + row];
    int n = cnt[base + row];
    int e = end - n;
    float acc = 0.f;
    while (e < end) {
        int m = min(64, end - e);
        float2 p = (lane < m) ? edge[e + lane] : make_float2(0.f, 0.f);
        int vidx = __float_as_int(p.x);
        int vval = __float_as_int(p.y);
        int j = 0;
        for (; j + 8 <= m; j += 8) {
            int i0 = __builtin_amdgcn_readlane(vidx, j + 0);
            int i1 = __builtin_amdgcn_readlane(vidx, j + 1);
            int i2 = __builtin_amdgcn_readlane(vidx, j + 2);
            int i3 = __builtin_amdgcn_readlane(vidx, j + 3);
            int i4 = __builtin_amdgcn_readlane(vidx, j + 4);
            int i5 = __builtin_amdgcn_readlane(vidx, j + 5);
            int i6 = __builtin_amdgcn_readlane(vidx, j + 6);
            int i7 = __builtin_amdgcn_readlane(vidx, j + 7);
            float g0 = Esrc[(size_t)i0 * 64 + lane];
            float g1 = Esrc[(size_t)i1 * 64 + lane];
            float g2 = Esrc[(size_t)i2 * 64 + lane];
            float g3 = Esrc[(size_t)i3 * 64 + lane];
            float g4 = Esrc[(size_t)i4 * 64 + lane];
            float g5 = Esrc[(size_t)i5 * 64 + lane];
            float g6 = Esrc[(size_t)i6 * 64 + lane];
            float g7 = Esrc[(size_t)i7 * 64 + lane];
            acc = __builtin_fmaf(rdlane_f(vval, j + 0), g0, acc);
            acc = __builtin_fmaf(rdlane_f(vval, j + 1), g1, acc);
            acc = __builtin_fmaf(rdlane_f(vval, j + 2), g2, acc);
            acc = __builtin_fmaf(rdlane_f(vval, j + 3), g3, acc);
            acc = __builtin_fmaf(rdlane_f(vval, j + 4), g4, acc);
            acc = __builtin_fmaf(rdlane_f(vval, j + 5), g5, acc);
            acc = __builtin_fmaf(rdlane_f(vval, j + 6), g6, acc);
            acc = __builtin_fmaf(rdlane_f(vval, j + 7), g7, acc);
        }
        for (; j < m; j++) {
            int i0 = __builtin_amdgcn_readlane(vidx, j);
            acc = __builtin_fmaf(rdlane_f(vval, j), Esrc[(size_t)i0 * 64 + lane], acc);
        }
        e += m;
    }
    size_t o = (size_t)row * 64 + lane;
    if (accum) out[o] += scale * acc;
    else out[o] = acc;
}

// rank reduction P[r][0:64] += sum_i W[r][i] * X[i][0:64]
// lane = g*16+t: float4 per lane, 4 rows per wave-iter (1KB coalesced loads);
// cross-g shfl reduce, per-block LDS combine, one 320-float atomic set per block.
// n must be divisible by 4 (100000 / 50000 both are).
__global__ __launch_bounds__(256) void rank_kernel(const float* __restrict__ X,
                                                   const float* __restrict__ W,
                                                   float* __restrict__ P, int n) {
    int lane = threadIdx.x & 63;
    int g = lane >> 4;
    int t = lane & 15;
    int wid = threadIdx.x >> 6;
    int wave = (blockIdx.x * blockDim.x + threadIdx.x) >> 6;
    int nw = (gridDim.x * blockDim.x) >> 6;
    int nq = n >> 2;
    float a[RANK][4];
#pragma unroll
    for (int r = 0; r < RANK; r++)
#pragma unroll
        for (int c = 0; c < 4; c++) a[r][c] = 0.f;
#pragma unroll 2
    for (int i4 = wave; i4 < nq; i4 += nw) {
        int row = i4 * 4 + g;
        float4 x = *(const float4*)(X + (size_t)row * 64 + t * 4);
#pragma unroll
        for (int r = 0; r < RANK; r++) {
            float w = W[(size_t)r * n + row];
            a[r][0] = __builtin_fmaf(w, x.x, a[r][0]);
            a[r][1] = __builtin_fmaf(w, x.y, a[r][1]);
            a[r][2] = __builtin_fmaf(w, x.z, a[r][2]);
            a[r][3] = __builtin_fmaf(w, x.w, a[r][3]);
        }
    }
#pragma unroll
    for (int r = 0; r < RANK; r++)
#pragma unroll
        for (int c = 0; c < 4; c++) {
            float v = a[r][c];
            v += __shfl_xor(v, 16);
            v += __shfl_xor(v, 32);
            a[r][c] = v;
        }
    __shared__ float ls[4][RANK * 64];
    if (g == 0) {
#pragma unroll
        for (int r = 0; r < RANK; r++)
#pragma unroll
            for (int c = 0; c < 4; c++) ls[wid][r * 64 + t * 4 + c] = a[r][c];
    }
    __syncthreads();
    int tid = threadIdx.x;
    if (tid < RANK * 64) {
        float s = ls[0][tid] + ls[1][tid] + ls[2][tid] + ls[3][tid];
        atomicAdd(&P[tid], s);
    }
}

__global__ void pre_out_kernel(const float4* __restrict__ a, const float4* __restrict__ b,
                               float4* __restrict__ o, int n) {
    int i = blockIdx.x * blockDim.x + threadIdx.x;
    if (i < n) {
        float4 x = a[i], y = b[i];
        const float s = 1.f / 3.f;
        o[i] = make_float4((x.x + y.x) * s, (x.y + y.y) * s, (x.z + y.z) * s, (x.w + y.w) * s);
    }
}

__global__ void conv_bf16_kernel(const float* __restrict__ E, short* __restrict__ B, int n64,
                                 int npad64) {
    int i = blockIdx.x * blockDim.x + threadIdx.x;
    if (i < npad64) B[i] = (i < n64) ? f2bf(E[i]) : (short)0;
}

__global__ void gather_kernel(const int* __restrict__ ids, int m, const float* __restrict__ E0,
                              const float* __restrict__ PQ, const float* __restrict__ mulS,
                              const float* __restrict__ Eout, short* __restrict__ Gb,
                              float* __restrict__ acc, float coef) {
    int lane = threadIdx.x & 63;
    int k = (blockIdx.x * blockDim.x + threadIdx.x) >> 6;
    if (k >= m) return;
    int u = ids[k];
    float g = E0[u * 64 + lane];
#pragma unroll
    for (int r = 0; r < RANK; r++) g = __builtin_fmaf(mulS[u * RANK + r], PQ[r * 64 + lane], g);
    g *= (1.f / 3.f);
    Gb[k * 64 + lane] = f2bf(g);
    float d = g * Eout[u * 64 + lane];
#pragma unroll
    for (int off = 32; off; off >>= 1) d += __shfl_down(d, off);
    if (lane == 0) {
        float t = fminf(fmaxf(d * 5.f, -5.f), 5.f);
        atomicAdd(acc, coef * t);
    }
}

// M-register-blocked neg-GEMM: each wave holds A for all 64 block rows (4 groups),
// sweeps CPW columns; per B-load-pair we issue 8 MFMAs + 16 exp-accumulates.
__global__ __launch_bounds__(256) void neg_mfma_kernel(const short* __restrict__ G16,
                                                       const short* __restrict__ E16,
                                                       float* __restrict__ part, int nchunk) {
    int lane = threadIdx.x & 63;
    int wave = threadIdx.x >> 6;
    int quad = lane >> 4;
    int rr = lane & 15;
    int rowbase = blockIdx.x * 64;
    short8 a0[4], a1[4];
#pragma unroll
    for (int g = 0; g < 4; g++) {
        const short8* ga = (const short8*)(G16 + (size_t)(rowbase + g * 16 + rr) * 64 + quad * 8);
        a0[g] = ga[0];
        a1[g] = ga[4];
    }
    int c0 = blockIdx.y * CPC + wave * CPW;
    float s[16];
#pragma unroll
    for (int i = 0; i < 16; i++) s[i] = 0.f;
    for (int ct = 0; ct < CPW; ct += 16) {
        const short8* eb = (const short8*)(E16 + (size_t)(c0 + ct + rr) * 64 + quad * 8);
        short8 b0 = eb[0];
        short8 b1 = eb[4];
#pragma unroll
        for (int g = 0; g < 4; g++) {
            floatx4 acc = {0.f, 0.f, 0.f, 0.f};
            acc = __builtin_amdgcn_mfma_f32_16x16x32_bf16(a0[g], b0, acc, 0, 0, 0);
            acc = __builtin_amdgcn_mfma_f32_16x16x32_bf16(a1[g], b1, acc, 0, 0, 0);
            s[g * 4 + 0] += __expf(acc[0] * 5.f);
            s[g * 4 + 1] += __expf(acc[1] * 5.f);
            s[g * 4 + 2] += __expf(acc[2] * 5.f);
            s[g * 4 + 3] += __expf(acc[3] * 5.f);
        }
    }
#pragma unroll
    for (int m = 8; m; m >>= 1) {
#pragma unroll
        for (int i = 0; i < 16; i++) s[i] += __shfl_xor(s[i], m);
    }
    if (rr == 0) {
        int col = blockIdx.y * 4 + wave;
#pragma unroll
        for (int g = 0; g < 4; g++) {
#pragma unroll
            for (int j = 0; j < 4; j++) {
                int row = rowbase + g * 16 + quad * 4 + j;
                part[(size_t)row * nchunk + col] = s[g * 4 + j];
            }
        }
    }
}

__global__ void combine_kernel(const float* __restrict__ part, int m, int nchunk, float pad,
                               float* __restrict__ acc, float coef) {
    int row = blockIdx.x * blockDim.x + threadIdx.x;
    if (row >= m) return;
    float S = 0.f;
    for (int c = 0; c < nchunk; c++) S += part[row * nchunk + c];
    float lse = __logf(S - pad);
    atomicAdd(acc, coef * lse);
}

__global__ void cat_kernel(const float* __restrict__ img, const float* __restrict__ txt,
                           float* __restrict__ out, int nrows) {
    int lane = threadIdx.x & 63;
    int row = (blockIdx.x * blockDim.x + threadIdx.x) >> 6;
    if (row >= nrows) return;
    float a = img[row * 64 + lane], b = txt[row * 64 + lane];
    float sa = a * a, sb = b * b;
#pragma unroll
    for (int msk = 32; msk; msk >>= 1) { sa += __shfl_xor(sa, msk); sb += __shfl_xor(sb, msk); }
    float ia = 1.f / fmaxf(sqrtf(sa), 1e-12f);
    float ib = 1.f / fmaxf(sqrtf(sb), 1e-12f);
    out[row * 64 + lane] += 0.02f * (a * ia + b * ib);
}

__global__ void loss_write_kernel(const float* __restrict__ acc, float* __restrict__ out) {
    out[0] = acc[0];
}

extern "C" void kernel_launch(void* const* d_in, const int* in_sizes, int n_in,
                              void* d_out, int out_size, void* d_ws, size_t ws_size,
                              hipStream_t stream) {
    const float* user_emb = (const float*)d_in[0];
    const float* item_emb = (const float*)d_in[1];
    const float* user_pre = (const float*)d_in[2];
    const float* item_pre = (const float*)d_in[3];
    const float* img_i = (const float*)d_in[4];
    const float* txt_i = (const float*)d_in[5];
    const float* img_u = (const float*)d_in[6];
    const float* txt_u = (const float*)d_in[7];
    const int* rows = (const int*)d_in[8];
    const int* cols = (const int*)d_in[9];
    const float* vals = (const float*)d_in[10];
    const float* ut = (const float*)d_in[11];
    const float* vt = (const float*)d_in[12];
    const float* u_mul_s = (const float*)d_in[13];
    const float* v_mul_s = (const float*)d_in[14];
    const int* uids = (const int*)d_in[15];
    const int* iids = (const int*)d_in[16];

    float* ws = (float*)d_ws;
    float* zu1 = ws + ZU1;
    float* zi1 = ws + ZI1;
    float2* edge = (float2*)(ws + EDGE);
    float* P = ws + P_OFF;
    float* Q = ws + Q_OFF;
    float* acc = ws + ACC_OFF;
    int* cnt = (int*)(ws + CNT_OFF);
    int* off = (int*)(ws + OFF_OFF);
    int* bcnt = (int*)(ws + BCNT_OFF);
    int* boff = (int*)(ws + BOFF_OFF);
    int* bsum = (int*)(ws + BSUM_OFF);
    float* eu0 = ws + EU0;
    float* ei0 = ws + EI0;
    float* part_u = ws + PART_U;
    float* part_i = ws + PART_I;
    int* bh = (int*)(ws + BH_OFF);
    int* bhp = (int*)(ws + BHP_OFF);
    float2* stage_sv = (float2*)(ws + STAGE_SV);
    short* ebu16 = (short*)(ws + EBU16);
    short* ebi16 = (short*)(ws + EBI16);
    short* gbu16 = (short*)(ws + GBU16);
    short* gbi16 = (short*)(ws + GBI16);

    float* out_u = (float*)d_out;
    float* out_i = out_u + (size_t)N_U * 64;
    float* out_loss = out_u + (size_t)(N_U + N_I) * 64;

    const int NB2 = (NBUCK + 255) / 256;  // 3 bucket-scan blocks

    // zero P,Q,acc only (cnt/off now written directly by place2)
    hipMemsetAsync(ws + P_OFF, 0, 704 * sizeof(float), stream);

    // ---- atomic-free CSR/CSC build ----
    bhist_kernel<<<NPB, 256, 0, stream>>>(rows, cols, bh);
    col_scan_kernel<<<NB2, 256, 0, stream>>>(bh, bhp, bcnt);
    scan1_kernel<<<NB2, 256, 0, stream>>>(bcnt, bsum, NBUCK);
    scan2_kernel<<<1, 1024, 0, stream>>>(bsum, NB2);
    scan3_kernel<<<NB2, 256, 0, stream>>>(bcnt, bsum, boff, NBUCK);
    bucket_place_kernel<<<NPB, 256, 0, stream>>>(rows, cols, vals, boff, bhp, stage_sv);
    place2_kernel<<<NBUCK, 256, 0, stream>>>(stage_sv, boff, bcnt, off, cnt, edge);

    // E0 = pre + emb
    ew_add_kernel<<<6250, 256, 0, stream>>>((const float4*)user_emb, (const float4*)user_pre,
                                            (float4*)eu0, 1600000);
    ew_add_kernel<<<3125, 256, 0, stream>>>((const float4*)item_emb, (const float4*)item_pre,
                                            (float4*)ei0, 800000);
    // layer-1 rank reductions
    rank_kernel<<<1024, 256, 0, stream>>>(ei0, vt, P, N_I);
    rank_kernel<<<1024, 256, 0, stream>>>(eu0, ut, Q, N_U);
    // layer-1 SpMM
    spmm_csr_kernel<<<N_U / 4, 256, 0, stream>>>(edge, off, cnt, 0, ei0, zu1, 1.f, 0, N_U);
    spmm_csr_kernel<<<N_I / 4, 256, 0, stream>>>(edge, off, cnt, N_U, eu0, zi1, 1.f, 0, N_I);
    // layer-2 rank reductions
    rank_kernel<<<1024, 256, 0, stream>>>(zi1, vt, P, N_I);
    rank_kernel<<<1024, 256, 0, stream>>>(zu1, ut, Q, N_U);
    // out = (E0 + Z1)/3, then layer-2 SpMM accumulates Z2/3 into out
    pre_out_kernel<<<6250, 256, 0, stream>>>((const float4*)eu0, (const float4*)zu1,
                                             (float4*)out_u, 1600000);
    pre_out_kernel<<<3125, 256, 0, stream>>>((const float4*)ei0, (const float4*)zi1,
                                             (float4*)out_i, 800000);
    spmm_csr_kernel<<<N_U / 4, 256, 0, stream>>>(edge, off, cnt, 0, zi1, out_u, 1.f / 3.f, 1,
                                                 N_U);
    spmm_csr_kernel<<<N_I / 4, 256, 0, stream>>>(edge, off, cnt, N_U, zu1, out_i, 1.f / 3.f, 1,
                                                 N_I);
    // bf16 copies of E (overlay in dead zu1 region; zero-padded tail rows)
    conv_bf16_kernel<<<(NPAD_U * 64 + 255) / 256, 256, 0, stream>>>(out_u, ebu16, N_U * 64,
                                                                   NPAD_U * 64);
    conv_bf16_kernel<<<(NPAD_I * 64 + 255) / 256, 256, 0, stream>>>(out_i, ebi16, N_I * 64,
                                                                   NPAD_I * 64);
    // sampled G rows (bf16) + pos term (fp32)
    gather_kernel<<<M_U / 4, 256, 0, stream>>>(uids, M_U, eu0, P, u_mul_s, out_u, gbu16, acc,
                                               -4.f / M_U);
    gather_kernel<<<M_I / 4, 256, 0, stream>>>(iids, M_I, ei0, Q, v_mul_s, out_i, gbi16, acc,
                                               -4.f / M_I);
    // neg term: MFMA exp-sum (4 chunk-columns per blockIdx.y: one per wave)
    dim3 gu(M_U / 64, NCH_U);
    neg_mfma_kernel<<<gu, 256, 0, stream>>>(gbu16, ebu16, part_u, NCH_U * 4);
    dim3 gi(M_I / 64, NCH_I);
    neg_mfma_kernel<<<gi, 256, 0, stream>>>(gbi16, ebi16, part_i, NCH_I * 4);
    combine_kernel<<<(M_U + 255) / 256, 256, 0, stream>>>(part_u, M_U, NCH_U * 4,
                                                          (float)(NPAD_U - N_U), acc, 4.f / M_U);
    combine_kernel<<<(M_I + 255) / 256, 256, 0, stream>>>(part_i, M_I, NCH_I * 4,
                                                          (float)(NPAD_I - N_I), acc, 4.f / M_I);
    // cat-rate terms (after loss consumed E from d_out)
    cat_kernel<<<(N_U * 64 + 255) / 256, 256, 0, stream>>>(img_u, txt_u, out_u, N_U);
    cat_kernel<<<(N_I * 64 + 255) / 256, 256, 0, stream>>>(img_i, txt_i, out_i, N_I);
    loss_write_kernel<<<1, 1, 0, stream>>>(acc, out_loss);
}

// Round 6
// 980.757 us; speedup vs baseline: 1.6258x; 1.0401x over previous
//
#include <hip/hip_runtime.h>
#include <cstdint>

#define N_U 100000
#define N_I 50000
#define DIM 64
#define RANK 5
#define NNZ_ 2000000
#define M_U 2048
#define M_I 4096
#define NSEG 150000   // N_U + N_I combined segment count
#define BSH 8         // bucket = seg >> 8  (256 segments per bucket)
#define NBUCK 586     // ceil(NSEG/256)
#define NPB 512       // place blocks
#define CH 3907       // edges per place block (ceil(NNZ_/NPB))

// neg-GEMM tiling
#define CPC 3136
#define CPW 784       // CPC/4, columns per wave
#define NCH_U 32
#define NCH_I 16
#define NPAD_U (CPC * NCH_U)
#define NPAD_I (CPC * NCH_I)

typedef __attribute__((ext_vector_type(8))) short short8;
typedef __attribute__((ext_vector_type(4))) float floatx4;

// ---- workspace layout (float offsets) ----
static constexpr size_t ZU1 = 0;                       // 6.4M
static constexpr size_t ZI1 = 6400000;                 // 3.2M
static constexpr size_t EDGE = 9600000;                // 4M packed uint edges = 4M floats
static constexpr size_t P_OFF = 13600000;              // 320
static constexpr size_t Q_OFF = 13600320;              // 320
static constexpr size_t ACC_OFF = 13600640;            // 1 (pad to 704)
static constexpr size_t CNT_OFF = 13600704;            // 150000 ints
static constexpr size_t OFF_OFF = 13750704;            // 150016 ints
static constexpr size_t BCNT_OFF = 13900720;           // NBUCK ints
static constexpr size_t BOFF_OFF = 13910144;           // NBUCK ints
static constexpr size_t BSUM_OFF = 13919552;           // 1024 ints
static constexpr size_t EU0 = 13920576;                // 6.4M
static constexpr size_t EI0 = EU0 + 6400000;           // 3.2M  -> ends 23,520,576
static constexpr size_t PART_U = EI0 + 3200000;        // 2048*128 = 262144
static constexpr size_t PART_I = PART_U + (size_t)M_U * NCH_U * 4;  // 4096*64 = 262144
static constexpr size_t GTU = PART_I + (size_t)M_I * NCH_I * 4;  // 3.2M fl = 6.4M ushort (bf16 of eu0 / zu1)
static constexpr size_t GTI = GTU + 3200000;           // 1.6M fl = 3.2M ushort (bf16 of ei0 / zi1)
// end = GTI + 1,600,000 = 28,844,864 floats = 115.4 MB (< 115.7 MB cap)
// ---- staging overlays, live ONLY during CSR build (before spmm / before place2) ----
static constexpr size_t STAGE_SV = 0;                  // 4M float2 over ZU1+ZI1
static constexpr size_t BH_OFF = EDGE;                 // NPB*NBUCK ints, dead before place2
static constexpr size_t BHP_OFF = EDGE + (size_t)NPB * NBUCK;  // NPB*NBUCK ints
// BH+BHP = 2*512*586 = 600,064 floats < 4M edge region ✓
// ---- bf16 overlay inside ZU1 (zu1/zi1 dead after pre_out; spmm-l2 gathers GT tables) ----
static constexpr size_t EBU16 = 0;                     // 3,211,264 fl
static constexpr size_t EBI16 = 3211264;               // 1,605,632 fl
static constexpr size_t GBU16 = EBI16 + 1605632;       // 65,536 fl
static constexpr size_t GBI16 = GBU16 + 65536;         // 131,072 fl -> end 5,013,504 < 6.4M

static __device__ __forceinline__ short f2bf(float x) {
    unsigned u = __builtin_bit_cast(unsigned, x);
    unsigned r = (u + 0x7fffu + ((u >> 16) & 1u)) >> 16;
    return (short)r;
}

static __device__ __forceinline__ float bfu(unsigned short u) {
    return __builtin_bit_cast(float, (unsigned)u << 16);
}

// decode 15-bit (signless) bf16 val from packed edge word
static __device__ __forceinline__ float vdec(unsigned p) {
    return __builtin_bit_cast(float, (p & 0x7FFFu) << 16);
}

__global__ void ew_add_kernel(const float4* __restrict__ a, const float4* __restrict__ b,
                              float4* __restrict__ o, int n) {
    int i = blockIdx.x * blockDim.x + threadIdx.x;
    if (i < n) {
        float4 x = a[i], y = b[i];
        o[i] = make_float4(x.x + y.x, x.y + y.y, x.z + y.z, x.w + y.w);
    }
}

// ---------- atomic-free CSR/CSC build ----------
// phase 1: per-block LDS bucket histogram, dense writeout bh[block][bucket]
__global__ __launch_bounds__(256) void bhist_kernel(const int* __restrict__ rows,
                                                    const int* __restrict__ cols,
                                                    int* __restrict__ bh) {
    __shared__ int h[NBUCK];
    for (int i = threadIdx.x; i < NBUCK; i += 256) h[i] = 0;
    __syncthreads();
    int b = blockIdx.x;
    int lo = b * CH, hi = min(lo + CH, NNZ_);
    for (int e = lo + threadIdx.x; e < hi; e += 256) {
        atomicAdd(&h[rows[e] >> BSH], 1);
        atomicAdd(&h[(N_U + cols[e]) >> BSH], 1);
    }
    __syncthreads();
    for (int i = threadIdx.x; i < NBUCK; i += 256) bh[(size_t)b * NBUCK + i] = h[i];
}

// phase 2: coalesced column scan: one thread per bucket, serial over NPB blocks.
__global__ __launch_bounds__(256) void col_scan_kernel(const int* __restrict__ bh,
                                                       int* __restrict__ bhp,
                                                       int* __restrict__ bcnt) {
    int j = blockIdx.x * 256 + threadIdx.x;
    if (j >= NBUCK) return;
    int run = 0;
#pragma unroll 16
    for (int b = 0; b < NPB; b++) {
        int v = bh[(size_t)b * NBUCK + j];
        bhp[(size_t)b * NBUCK + j] = run;
        run += v;
    }
    bcnt[j] = run;
}

__global__ void scan1_kernel(const int* __restrict__ cnt, int* __restrict__ bsum, int n) {
    int i = blockIdx.x * 256 + threadIdx.x;
    int v = (i < n) ? cnt[i] : 0;
#pragma unroll
    for (int off = 32; off; off >>= 1) v += __shfl_down(v, off);
    __shared__ int ls[4];
    int lane = threadIdx.x & 63, w = threadIdx.x >> 6;
    if (lane == 0) ls[w] = v;
    __syncthreads();
    if (threadIdx.x == 0) bsum[blockIdx.x] = ls[0] + ls[1] + ls[2] + ls[3];
}

__global__ void scan2_kernel(int* __restrict__ bsum, int nb) {
    __shared__ int s[1024];
    int t = threadIdx.x;
    s[t] = (t < nb) ? bsum[t] : 0;
    __syncthreads();
    for (int off = 1; off < 1024; off <<= 1) {
        int v = (t >= off) ? s[t - off] : 0;
        __syncthreads();
        s[t] += v;
        __syncthreads();
    }
    if (t < nb) bsum[t] = (t == 0) ? 0 : s[t - 1];
}

__global__ void scan3_kernel(const int* __restrict__ cnt, const int* __restrict__ bsum,
                             int* __restrict__ off, int n) {
    __shared__ int s[256];
    int i = blockIdx.x * 256 + threadIdx.x;
    int t = threadIdx.x;
    int c = (i < n) ? cnt[i] : 0;
    s[t] = c;
    __syncthreads();
    for (int o = 1; o < 256; o <<= 1) {
        int v = (t >= o) ? s[t - o] : 0;
        __syncthreads();
        s[t] += v;
        __syncthreads();
    }
    if (i < n) off[i] = bsum[blockIdx.x] + s[t] - c;
}

// phase 3: deterministic placement into bucket-grouped staging (no global atomics).
// entry = (idx | (seg&255)<<20, val) -- idx < 2^20, 8-bit tag recovers segment in place2.
__global__ __launch_bounds__(256) void bucket_place_kernel(
    const int* __restrict__ rows, const int* __restrict__ cols, const float* __restrict__ vals,
    const int* __restrict__ boff, const int* __restrict__ bhp, float2* __restrict__ sv) {
    __shared__ int h[NBUCK];
    for (int i = threadIdx.x; i < NBUCK; i += 256) h[i] = 0;
    __syncthreads();
    int b = blockIdx.x;
    int lo = b * CH, hi = min(lo + CH, NNZ_);
    const int* bhpb = bhp + (size_t)b * NBUCK;
    for (int e = lo + threadIdx.x; e < hi; e += 256) {
        int r = rows[e], c = cols[e];
        float v = vals[e];
        int bu = r >> BSH;
        int ru = atomicAdd(&h[bu], 1);
        sv[boff[bu] + bhpb[bu] + ru] = make_float2(__int_as_float(c | ((r & 255) << 20)), v);
        int sI = N_U + c;
        int bi = sI >> BSH;
        int ri = atomicAdd(&h[bi], 1);
        sv[boff[bi] + bhpb[bi] + ri] = make_float2(__int_as_float(r | ((sI & 255) << 20)), v);
    }
}

// phase 4: one block per bucket: exact CSR placement of its ~6.8K entries.
// Final edge = idx(17b)<<15 | bf16(val)(15b, sign=0: vals >= 0) -- 4 bytes/edge.
__global__ __launch_bounds__(256) void place2_kernel(const float2* __restrict__ sv,
                                                     const int* __restrict__ boff,
                                                     const int* __restrict__ bcnt,
                                                     int* __restrict__ off, int* __restrict__ cnt,
                                                     unsigned* __restrict__ edge) {
    int b = blockIdx.x;
    int start = boff[b], n = bcnt[b];
    __shared__ int h[256], hs[256], hc[256];
    h[threadIdx.x] = 0;
    hc[threadIdx.x] = 0;
    __syncthreads();
    for (int i = start + threadIdx.x; i < start + n; i += 256) {
        int packed = __float_as_int(sv[i].x);
        atomicAdd(&h[(packed >> 20) & 255], 1);
    }
    __syncthreads();
    if (threadIdx.x == 0) {
        int run = 0;
#pragma unroll
        for (int k = 0; k < 256; k++) { hs[k] = run; run += h[k]; }
    }
    __syncthreads();
    {
        int seg = b * 256 + threadIdx.x;
        if (seg < NSEG) {
            cnt[seg] = h[threadIdx.x];
            off[seg] = start + hs[threadIdx.x] + h[threadIdx.x];  // END offsets (spmm convention)
        }
    }
    for (int i = start + threadIdx.x; i < start + n; i += 256) {
        float2 p = sv[i];
        int packed = __float_as_int(p.x);
        int s = (packed >> 20) & 255;
        int r = atomicAdd(&hc[s], 1);
        unsigned vb = (unsigned)(unsigned short)f2bf(p.y);
        edge[start + hs[s] + r] = ((unsigned)(packed & 0xFFFFF) << 15) | (vb & 0x7FFFu);
    }
}

// wave-per-row CSR SpMM over 4-byte packed edges + bf16 gather table.
// off[] holds END offsets, range = [end-cnt, end).
// Wave loads <=64 edges in ONE coalesced 256B read, broadcasts via readlane
// (one per edge decodes idx+val), issues 8 independent 128B gathers per round.
__global__ __launch_bounds__(256) void spmm_csr_kernel(
    const unsigned* __restrict__ edge, const int* __restrict__ off, const int* __restrict__ cnt,
    int base, const unsigned short* __restrict__ E16, float* __restrict__ out, float scale,
    int accum, int nrows) {
    int lane = threadIdx.x & 63;
    int row = (blockIdx.x * blockDim.x + threadIdx.x) >> 6;
    if (row >= nrows) return;
    int end = off[base + row];
    int n = cnt[base + row];
    int e = end - n;
    float acc = 0.f;
    while (e < end) {
        int m = min(64, end - e);
        unsigned pk = (lane < m) ? edge[e + lane] : 0u;
        int j = 0;
        for (; j + 8 <= m; j += 8) {
            unsigned p0 = (unsigned)__builtin_amdgcn_readlane((int)pk, j + 0);
            unsigned p1 = (unsigned)__builtin_amdgcn_readlane((int)pk, j + 1);
            unsigned p2 = (unsigned)__builtin_amdgcn_readlane((int)pk, j + 2);
            unsigned p3 = (unsigned)__builtin_amdgcn_readlane((int)pk, j + 3);
            unsigned p4 = (unsigned)__builtin_amdgcn_readlane((int)pk, j + 4);
            unsigned p5 = (unsigned)__builtin_amdgcn_readlane((int)pk, j + 5);
            unsigned p6 = (unsigned)__builtin_amdgcn_readlane((int)pk, j + 6);
            unsigned p7 = (unsigned)__builtin_amdgcn_readlane((int)pk, j + 7);
            float g0 = bfu(E16[(size_t)(p0 >> 15) * 64 + lane]);
            float g1 = bfu(E16[(size_t)(p1 >> 15) * 64 + lane]);
            float g2 = bfu(E16[(size_t)(p2 >> 15) * 64 + lane]);
            float g3 = bfu(E16[(size_t)(p3 >> 15) * 64 + lane]);
            float g4 = bfu(E16[(size_t)(p4 >> 15) * 64 + lane]);
            float g5 = bfu(E16[(size_t)(p5 >> 15) * 64 + lane]);
            float g6 = bfu(E16[(size_t)(p6 >> 15) * 64 + lane]);
            float g7 = bfu(E16[(size_t)(p7 >> 15) * 64 + lane]);
            acc = __builtin_fmaf(vdec(p0), g0, acc);
            acc = __builtin_fmaf(vdec(p1), g1, acc);
            acc = __builtin_fmaf(vdec(p2), g2, acc);
            acc = __builtin_fmaf(vdec(p3), g3, acc);
            acc = __builtin_fmaf(vdec(p4), g4, acc);
            acc = __builtin_fmaf(vdec(p5), g5, acc);
            acc = __builtin_fmaf(vdec(p6), g6, acc);
            acc = __builtin_fmaf(vdec(p7), g7, acc);
        }
        for (; j < m; j++) {
            unsigned p = (unsigned)__builtin_amdgcn_readlane((int)pk, j);
            acc = __builtin_fmaf(vdec(p), bfu(E16[(size_t)(p >> 15) * 64 + lane]), acc);
        }
        e += m;
    }
    size_t o = (size_t)row * 64 + lane;
    if (accum) out[o] += scale * acc;
    else out[o] = acc;
}

// rank reduction P[r][0:64] += sum_i W[r][i] * X[i][0:64]
// lane = g*16+t: float4 per lane, 4 rows per wave-iter (1KB coalesced loads);
// cross-g shfl reduce, per-block LDS combine, one 320-float atomic set per block.
__global__ __launch_bounds__(256) void rank_kernel(const float* __restrict__ X,
                                                   const float* __restrict__ W,
                                                   float* __restrict__ P, int n) {
    int lane = threadIdx.x & 63;
    int g = lane >> 4;
    int t = lane & 15;
    int wid = threadIdx.x >> 6;
    int wave = (blockIdx.x * blockDim.x + threadIdx.x) >> 6;
    int nw = (gridDim.x * blockDim.x) >> 6;
    int nq = n >> 2;
    float a[RANK][4];
#pragma unroll
    for (int r = 0; r < RANK; r++)
#pragma unroll
        for (int c = 0; c < 4; c++) a[r][c] = 0.f;
#pragma unroll 2
    for (int i4 = wave; i4 < nq; i4 += nw) {
        int row = i4 * 4 + g;
        float4 x = *(const float4*)(X + (size_t)row * 64 + t * 4);
#pragma unroll
        for (int r = 0; r < RANK; r++) {
            float w = W[(size_t)r * n + row];
            a[r][0] = __builtin_fmaf(w, x.x, a[r][0]);
            a[r][1] = __builtin_fmaf(w, x.y, a[r][1]);
            a[r][2] = __builtin_fmaf(w, x.z, a[r][2]);
            a[r][3] = __builtin_fmaf(w, x.w, a[r][3]);
        }
    }
#pragma unroll
    for (int r = 0; r < RANK; r++)
#pragma unroll
        for (int c = 0; c < 4; c++) {
            float v = a[r][c];
            v += __shfl_xor(v, 16);
            v += __shfl_xor(v, 32);
            a[r][c] = v;
        }
    __shared__ float ls[4][RANK * 64];
    if (g == 0) {
#pragma unroll
        for (int r = 0; r < RANK; r++)
#pragma unroll
            for (int c = 0; c < 4; c++) ls[wid][r * 64 + t * 4 + c] = a[r][c];
    }
    __syncthreads();
    int tid = threadIdx.x;
    if (tid < RANK * 64) {
        float s = ls[0][tid] + ls[1][tid] + ls[2][tid] + ls[3][tid];
        atomicAdd(&P[tid], s);
    }
}

__global__ void pre_out_kernel(const float4* __restrict__ a, const float4* __restrict__ b,
                               float4* __restrict__ o, int n) {
    int i = blockIdx.x * blockDim.x + threadIdx.x;
    if (i < n) {
        float4 x = a[i], y = b[i];
        const float s = 1.f / 3.f;
        o[i] = make_float4((x.x + y.x) * s, (x.y + y.y) * s, (x.z + y.z) * s, (x.w + y.w) * s);
    }
}

__global__ void conv_bf16_kernel(const float* __restrict__ E, short* __restrict__ B, int n64,
                                 int npad64) {
    int i = blockIdx.x * blockDim.x + threadIdx.x;
    if (i < npad64) B[i] = (i < n64) ? f2bf(E[i]) : (short)0;
}

__global__ void gather_kernel(const int* __restrict__ ids, int m, const float* __restrict__ E0,
                              const float* __restrict__ PQ, const float* __restrict__ mulS,
                              const float* __restrict__ Eout, short* __restrict__ Gb,
                              float* __restrict__ acc, float coef) {
    int lane = threadIdx.x & 63;
    int k = (blockIdx.x * blockDim.x + threadIdx.x) >> 6;
    if (k >= m) return;
    int u = ids[k];
    float g = E0[u * 64 + lane];
#pragma unroll
    for (int r = 0; r < RANK; r++) g = __builtin_fmaf(mulS[u * RANK + r], PQ[r * 64 + lane], g);
    g *= (1.f / 3.f);
    Gb[k * 64 + lane] = f2bf(g);
    float d = g * Eout[u * 64 + lane];
#pragma unroll
    for (int off = 32; off; off >>= 1) d += __shfl_down(d, off);
    if (lane == 0) {
        float t = fminf(fmaxf(d * 5.f, -5.f), 5.f);
        atomicAdd(acc, coef * t);
    }
}

// M-register-blocked neg-GEMM: each wave holds A for all 64 block rows (4 groups),
// sweeps CPW columns; per B-load-pair we issue 8 MFMAs + 16 exp-accumulates.
__global__ __launch_bounds__(256) void neg_mfma_kernel(const short* __restrict__ G16,
                                                       const short* __restrict__ E16,
                                                       float* __restrict__ part, int nchunk) {
    int lane = threadIdx.x & 63;
    int wave = threadIdx.x >> 6;
    int quad = lane >> 4;
    int rr = lane & 15;
    int rowbase = blockIdx.x * 64;
    short8 a0[4], a1[4];
#pragma unroll
    for (int g = 0; g < 4; g++) {
        const short8* ga = (const short8*)(G16 + (size_t)(rowbase + g * 16 + rr) * 64 + quad * 8);
        a0[g] = ga[0];
        a1[g] = ga[4];
    }
    int c0 = blockIdx.y * CPC + wave * CPW;
    float s[16];
#pragma unroll
    for (int i = 0; i < 16; i++) s[i] = 0.f;
    for (int ct = 0; ct < CPW; ct += 16) {
        const short8* eb = (const short8*)(E16 + (size_t)(c0 + ct + rr) * 64 + quad * 8);
        short8 b0 = eb[0];
        short8 b1 = eb[4];
#pragma unroll
        for (int g = 0; g < 4; g++) {
            floatx4 acc = {0.f, 0.f, 0.f, 0.f};
            acc = __builtin_amdgcn_mfma_f32_16x16x32_bf16(a0[g], b0, acc, 0, 0, 0);
            acc = __builtin_amdgcn_mfma_f32_16x16x32_bf16(a1[g], b1, acc, 0, 0, 0);
            s[g * 4 + 0] += __expf(acc[0] * 5.f);
            s[g * 4 + 1] += __expf(acc[1] * 5.f);
            s[g * 4 + 2] += __expf(acc[2] * 5.f);
            s[g * 4 + 3] += __expf(acc[3] * 5.f);
        }
    }
#pragma unroll
    for (int m = 8; m; m >>= 1) {
#pragma unroll
        for (int i = 0; i < 16; i++) s[i] += __shfl_xor(s[i], m);
    }
    if (rr == 0) {
        int col = blockIdx.y * 4 + wave;
#pragma unroll
        for (int g = 0; g < 4; g++) {
#pragma unroll
            for (int j = 0; j < 4; j++) {
                int row = rowbase + g * 16 + quad * 4 + j;
                part[(size_t)row * nchunk + col] = s[g * 4 + j];
            }
        }
    }
}

__global__ void combine_kernel(const float* __restrict__ part, int m, int nchunk, float pad,
                               float* __restrict__ acc, float coef) {
    int row = blockIdx.x * blockDim.x + threadIdx.x;
    if (row >= m) return;
    float S = 0.f;
    for (int c = 0; c < nchunk; c++) S += part[row * nchunk + c];
    float lse = __logf(S - pad);
    atomicAdd(acc, coef * lse);
}

__global__ void cat_kernel(const float* __restrict__ img, const float* __restrict__ txt,
                           float* __restrict__ out, int nrows) {
    int lane = threadIdx.x & 63;
    int row = (blockIdx.x * blockDim.x + threadIdx.x) >> 6;
    if (row >= nrows) return;
    float a = img[row * 64 + lane], b = txt[row * 64 + lane];
    float sa = a * a, sb = b * b;
#pragma unroll
    for (int msk = 32; msk; msk >>= 1) { sa += __shfl_xor(sa, msk); sb += __shfl_xor(sb, msk); }
    float ia = 1.f / fmaxf(sqrtf(sa), 1e-12f);
    float ib = 1.f / fmaxf(sqrtf(sb), 1e-12f);
    out[row * 64 + lane] += 0.02f * (a * ia + b * ib);
}

__global__ void loss_write_kernel(const float* __restrict__ acc, float* __restrict__ out) {
    out[0] = acc[0];
}

extern "C" void kernel_launch(void* const* d_in, const int* in_sizes, int n_in,
                              void* d_out, int out_size, void* d_ws, size_t ws_size,
                              hipStream_t stream) {
    const float* user_emb = (const float*)d_in[0];
    const float* item_emb = (const float*)d_in[1];
    const float* user_pre = (const float*)d_in[2];
    const float* item_pre = (const float*)d_in[3];
    const float* img_i = (const float*)d_in[4];
    const float* txt_i = (const float*)d_in[5];
    const float* img_u = (const float*)d_in[6];
    const float* txt_u = (const float*)d_in[7];
    const int* rows = (const int*)d_in[8];
    const int* cols = (const int*)d_in[9];
    const float* vals = (const float*)d_in[10];
    const float* ut = (const float*)d_in[11];
    const float* vt = (const float*)d_in[12];
    const float* u_mul_s = (const float*)d_in[13];
    const float* v_mul_s = (const float*)d_in[14];
    const int* uids = (const int*)d_in[15];
    const int* iids = (const int*)d_in[16];

    float* ws = (float*)d_ws;
    float* zu1 = ws + ZU1;
    float* zi1 = ws + ZI1;
    unsigned* edge = (unsigned*)(ws + EDGE);
    float* P = ws + P_OFF;
    float* Q = ws + Q_OFF;
    float* acc = ws + ACC_OFF;
    int* cnt = (int*)(ws + CNT_OFF);
    int* off = (int*)(ws + OFF_OFF);
    int* bcnt = (int*)(ws + BCNT_OFF);
    int* boff = (int*)(ws + BOFF_OFF);
    int* bsum = (int*)(ws + BSUM_OFF);
    float* eu0 = ws + EU0;
    float* ei0 = ws + EI0;
    float* part_u = ws + PART_U;
    float* part_i = ws + PART_I;
    unsigned short* gtu = (unsigned short*)(ws + GTU);
    unsigned short* gti = (unsigned short*)(ws + GTI);
    int* bh = (int*)(ws + BH_OFF);
    int* bhp = (int*)(ws + BHP_OFF);
    float2* stage_sv = (float2*)(ws + STAGE_SV);
    short* ebu16 = (short*)(ws + EBU16);
    short* ebi16 = (short*)(ws + EBI16);
    short* gbu16 = (short*)(ws + GBU16);
    short* gbi16 = (short*)(ws + GBI16);

    float* out_u = (float*)d_out;
    float* out_i = out_u + (size_t)N_U * 64;
    float* out_loss = out_u + (size_t)(N_U + N_I) * 64;

    const int NB2 = (NBUCK + 255) / 256;  // 3 bucket-scan blocks

    // zero P,Q,acc only (cnt/off now written directly by place2)
    hipMemsetAsync(ws + P_OFF, 0, 704 * sizeof(float), stream);

    // ---- atomic-free CSR/CSC build ----
    bhist_kernel<<<NPB, 256, 0, stream>>>(rows, cols, bh);
    col_scan_kernel<<<NB2, 256, 0, stream>>>(bh, bhp, bcnt);
    scan1_kernel<<<NB2, 256, 0, stream>>>(bcnt, bsum, NBUCK);
    scan2_kernel<<<1, 1024, 0, stream>>>(bsum, NB2);
    scan3_kernel<<<NB2, 256, 0, stream>>>(bcnt, bsum, boff, NBUCK);
    bucket_place_kernel<<<NPB, 256, 0, stream>>>(rows, cols, vals, boff, bhp, stage_sv);
    place2_kernel<<<NBUCK, 256, 0, stream>>>(stage_sv, boff, bcnt, off, cnt, edge);

    // E0 = pre + emb
    ew_add_kernel<<<6250, 256, 0, stream>>>((const float4*)user_emb, (const float4*)user_pre,
                                            (float4*)eu0, 1600000);
    ew_add_kernel<<<3125, 256, 0, stream>>>((const float4*)item_emb, (const float4*)item_pre,
                                            (float4*)ei0, 800000);
    // bf16 gather tables for layer-1 spmm
    conv_bf16_kernel<<<12500, 256, 0, stream>>>(ei0, (short*)gti, N_I * 64, N_I * 64);
    conv_bf16_kernel<<<25000, 256, 0, stream>>>(eu0, (short*)gtu, N_U * 64, N_U * 64);
    // layer-1 rank reductions
    rank_kernel<<<1024, 256, 0, stream>>>(ei0, vt, P, N_I);
    rank_kernel<<<1024, 256, 0, stream>>>(eu0, ut, Q, N_U);
    // layer-1 SpMM (bf16 gather)
    spmm_csr_kernel<<<N_U / 4, 256, 0, stream>>>(edge, off, cnt, 0, gti, zu1, 1.f, 0, N_U);
    spmm_csr_kernel<<<N_I / 4, 256, 0, stream>>>(edge, off, cnt, N_U, gtu, zi1, 1.f, 0, N_I);
    // bf16 gather tables for layer-2 spmm (overwrite)
    conv_bf16_kernel<<<12500, 256, 0, stream>>>(zi1, (short*)gti, N_I * 64, N_I * 64);
    conv_bf16_kernel<<<25000, 256, 0, stream>>>(zu1, (short*)gtu, N_U * 64, N_U * 64);
    // layer-2 rank reductions
    rank_kernel<<<1024, 256, 0, stream>>>(zi1, vt, P, N_I);
    rank_kernel<<<1024, 256, 0, stream>>>(zu1, ut, Q, N_U);
    // out = (E0 + Z1)/3, then layer-2 SpMM accumulates Z2/3 into out
    pre_out_kernel<<<6250, 256, 0, stream>>>((const float4*)eu0, (const float4*)zu1,
                                             (float4*)out_u, 1600000);
    pre_out_kernel<<<3125, 256, 0, stream>>>((const float4*)ei0, (const float4*)zi1,
                                             (float4*)out_i, 800000);
    spmm_csr_kernel<<<N_U / 4, 256, 0, stream>>>(edge, off, cnt, 0, gti, out_u, 1.f / 3.f, 1,
                                                 N_U);
    spmm_csr_kernel<<<N_I / 4, 256, 0, stream>>>(edge, off, cnt, N_U, gtu, out_i, 1.f / 3.f, 1,
                                                 N_I);
    // bf16 copies of E (overlay in dead zu1 region; zero-padded tail rows)
    conv_bf16_kernel<<<(NPAD_U * 64 + 255) / 256, 256, 0, stream>>>(out_u, ebu16, N_U * 64,
                                                                   NPAD_U * 64);
    conv_bf16_kernel<<<(NPAD_I * 64 + 255) / 256, 256, 0, stream>>>(out_i, ebi16, N_I * 64,
                                                                   NPAD_I * 64);
    // sampled G rows (bf16) + pos term (fp32)
    gather_kernel<<<M_U / 4, 256, 0, stream>>>(uids, M_U, eu0, P, u_mul_s, out_u, gbu16, acc,
                                               -4.f / M_U);
    gather_kernel<<<M_I / 4, 256, 0, stream>>>(iids, M_I, ei0, Q, v_mul_s, out_i, gbi16, acc,
                                               -4.f / M_I);
    // neg term: MFMA exp-sum (4 chunk-columns per blockIdx.y: one per wave)
    dim3 gu(M_U / 64, NCH_U);
    neg_mfma_kernel<<<gu, 256, 0, stream>>>(gbu16, ebu16, part_u, NCH_U * 4);
    dim3 gi(M_I / 64, NCH_I);
    neg_mfma_kernel<<<gi, 256, 0, stream>>>(gbi16, ebi16, part_i, NCH_I * 4);
    combine_kernel<<<(M_U + 255) / 256, 256, 0, stream>>>(part_u, M_U, NCH_U * 4,
                                                          (float)(NPAD_U - N_U), acc, 4.f / M_U);
    combine_kernel<<<(M_I + 255) / 256, 256, 0, stream>>>(part_i, M_I, NCH_I * 4,
                                                          (float)(NPAD_I - N_I), acc, 4.f / M_I);
    // cat-rate terms (after loss consumed E from d_out)
    cat_kernel<<<(N_U * 64 + 255) / 256, 256, 0, stream>>>(img_u, txt_u, out_u, N_U);
    cat_kernel<<<(N_I * 64 + 255) / 256, 256, 0, stream>>>(img_i, txt_i, out_i, N_I);
    loss_write_kernel<<<1, 1, 0, stream>>>(acc, out_loss);
}

// Round 7
// 892.058 us; speedup vs baseline: 1.7874x; 1.0994x over previous
//
#include <hip/hip_runtime.h>
#include <cstdint>

#define N_U 100000
#define N_I 50000
#define DIM 64
#define RANK 5
#define NNZ_ 2000000
#define M_U 2048
#define M_I 4096
#define NSEG 150000   // N_U + N_I combined segment count
#define BSH 9         // bucket = seg >> 9  (512 segments per bucket)
#define SPB 512       // segments per bucket
#define NBUCK 293     // ceil(NSEG/512)
#define NPB 1024      // place blocks
#define CH 1954       // edges per place block (ceil(NNZ_/NPB))

// neg-GEMM tiling
#define CPC 3136
#define CPW 784       // CPC/4, columns per wave
#define NCH_U 32
#define NCH_I 16
#define NPAD_U (CPC * NCH_U)
#define NPAD_I (CPC * NCH_I)

typedef __attribute__((ext_vector_type(8))) short short8;
typedef __attribute__((ext_vector_type(4))) short short4v;
typedef __attribute__((ext_vector_type(4))) float floatx4;

// ---- workspace layout (float offsets) ----
static constexpr size_t ZU1 = 0;                       // 6.4M
static constexpr size_t ZI1 = 6400000;                 // 3.2M
static constexpr size_t EDGE = 9600000;                // 4M packed uint edges = 4M floats
static constexpr size_t P_OFF = 13600000;              // 320
static constexpr size_t Q_OFF = 13600320;              // 320
static constexpr size_t ACC_OFF = 13600640;            // 1 (pad to 704)
static constexpr size_t CNT_OFF = 13600704;            // 150000 ints
static constexpr size_t OFF_OFF = 13750704;            // 150016 ints
static constexpr size_t BCNT_OFF = 13900720;           // NBUCK ints
static constexpr size_t BOFF_OFF = 13910144;           // NBUCK ints
static constexpr size_t BSUM_OFF = 13919552;           // 1024 ints
static constexpr size_t EU0 = 13920576;                // 6.4M
static constexpr size_t EI0 = EU0 + 6400000;           // 3.2M  -> ends 23,520,576
static constexpr size_t PART_U = EI0 + 3200000;        // 2048*128 = 262144
static constexpr size_t PART_I = PART_U + (size_t)M_U * NCH_U * 4;  // 4096*64 = 262144
static constexpr size_t GTU = PART_I + (size_t)M_I * NCH_I * 4;  // bf16 of eu0 / zu1
static constexpr size_t GTI = GTU + 3200000;           // bf16 of ei0 / zi1
// end = GTI + 1,600,000 = 28,844,864 floats = 115.4 MB (< 115.7 MB cap)
// ---- staging overlays, live ONLY during CSR build (before spmm / before place2) ----
static constexpr size_t STAGE_SV = 0;                  // 4M float2 over ZU1+ZI1
static constexpr size_t BH_OFF = EDGE;                 // NPB*NBUCK ints, dead before place2
static constexpr size_t BHP_OFF = EDGE + (size_t)NPB * NBUCK;  // NPB*NBUCK ints
// BH+BHP = 2*1024*293 = 600,064 floats < 4M edge region ✓
// ---- bf16 overlay inside ZU1 (zu1/zi1 dead after pre_out; spmm-l2 gathers GT tables) ----
static constexpr size_t EBU16 = 0;                     // 3,211,264 fl
static constexpr size_t EBI16 = 3211264;               // 1,605,632 fl
static constexpr size_t GBU16 = EBI16 + 1605632;       // 65,536 fl
static constexpr size_t GBI16 = GBU16 + 65536;         // 131,072 fl -> end 5,013,504 < 6.4M

static __device__ __forceinline__ short f2bf(float x) {
    unsigned u = __builtin_bit_cast(unsigned, x);
    unsigned r = (u + 0x7fffu + ((u >> 16) & 1u)) >> 16;
    return (short)r;
}

static __device__ __forceinline__ float bfu(unsigned short u) {
    return __builtin_bit_cast(float, (unsigned)u << 16);
}

// decode 15-bit (signless) bf16 val from packed edge word
static __device__ __forceinline__ float vdec(unsigned p) {
    return __builtin_bit_cast(float, (p & 0x7FFFu) << 16);
}

__global__ void ew_add_kernel(const float4* __restrict__ a, const float4* __restrict__ b,
                              float4* __restrict__ o, int n) {
    int i = blockIdx.x * blockDim.x + threadIdx.x;
    if (i < n) {
        float4 x = a[i], y = b[i];
        o[i] = make_float4(x.x + y.x, x.y + y.y, x.z + y.z, x.w + y.w);
    }
}

// ---------- atomic-free CSR/CSC build ----------
// phase 1: per-block LDS bucket histogram, dense writeout bh[block][bucket]
__global__ __launch_bounds__(256) void bhist_kernel(const int* __restrict__ rows,
                                                    const int* __restrict__ cols,
                                                    int* __restrict__ bh) {
    __shared__ int h[NBUCK];
    for (int i = threadIdx.x; i < NBUCK; i += 256) h[i] = 0;
    __syncthreads();
    int b = blockIdx.x;
    int lo = b * CH, hi = min(lo + CH, NNZ_);
    for (int e = lo + threadIdx.x; e < hi; e += 256) {
        atomicAdd(&h[rows[e] >> BSH], 1);
        atomicAdd(&h[(N_U + cols[e]) >> BSH], 1);
    }
    __syncthreads();
    for (int i = threadIdx.x; i < NBUCK; i += 256) bh[(size_t)b * NBUCK + i] = h[i];
}

// phase 2: coalesced column scan: one thread per bucket, serial over NPB blocks.
__global__ __launch_bounds__(256) void col_scan_kernel(const int* __restrict__ bh,
                                                       int* __restrict__ bhp,
                                                       int* __restrict__ bcnt) {
    int j = blockIdx.x * 256 + threadIdx.x;
    if (j >= NBUCK) return;
    int run = 0;
#pragma unroll 16
    for (int b = 0; b < NPB; b++) {
        int v = bh[(size_t)b * NBUCK + j];
        bhp[(size_t)b * NBUCK + j] = run;
        run += v;
    }
    bcnt[j] = run;
}

__global__ void scan1_kernel(const int* __restrict__ cnt, int* __restrict__ bsum, int n) {
    int i = blockIdx.x * 256 + threadIdx.x;
    int v = (i < n) ? cnt[i] : 0;
#pragma unroll
    for (int off = 32; off; off >>= 1) v += __shfl_down(v, off);
    __shared__ int ls[4];
    int lane = threadIdx.x & 63, w = threadIdx.x >> 6;
    if (lane == 0) ls[w] = v;
    __syncthreads();
    if (threadIdx.x == 0) bsum[blockIdx.x] = ls[0] + ls[1] + ls[2] + ls[3];
}

__global__ void scan2_kernel(int* __restrict__ bsum, int nb) {
    __shared__ int s[1024];
    int t = threadIdx.x;
    s[t] = (t < nb) ? bsum[t] : 0;
    __syncthreads();
    for (int off = 1; off < 1024; off <<= 1) {
        int v = (t >= off) ? s[t - off] : 0;
        __syncthreads();
        s[t] += v;
        __syncthreads();
    }
    if (t < nb) bsum[t] = (t == 0) ? 0 : s[t - 1];
}

__global__ void scan3_kernel(const int* __restrict__ cnt, const int* __restrict__ bsum,
                             int* __restrict__ off, int n) {
    __shared__ int s[256];
    int i = blockIdx.x * 256 + threadIdx.x;
    int t = threadIdx.x;
    int c = (i < n) ? cnt[i] : 0;
    s[t] = c;
    __syncthreads();
    for (int o = 1; o < 256; o <<= 1) {
        int v = (t >= o) ? s[t - o] : 0;
        __syncthreads();
        s[t] += v;
        __syncthreads();
    }
    if (i < n) off[i] = bsum[blockIdx.x] + s[t] - c;
}

// phase 3: LDS-staged placement -> coalesced global writeout.
// Block's histogram comes from bh (computed by bhist); entries are bucket-sorted
// into LDS (buf/bid), then streamed out: consecutive p -> consecutive dst within
// each (block,bucket) chunk.  entry = (idx | (seg&511)<<20, val), idx < 2^20.
__global__ __launch_bounds__(256) void bucket_place_kernel(
    const int* __restrict__ rows, const int* __restrict__ cols, const float* __restrict__ vals,
    const int* __restrict__ boff, const int* __restrict__ bh, const int* __restrict__ bhp,
    float2* __restrict__ sv) {
    __shared__ int h[NBUCK], ls[NBUCK], gb[NBUCK];
    __shared__ int sc[256];
    __shared__ float2 buf[2 * CH];
    __shared__ unsigned short bid[2 * CH];
    int tid = threadIdx.x;
    int b = blockIdx.x;
    const int* bhrow = bh + (size_t)b * NBUCK;
    const int* bhprow = bhp + (size_t)b * NBUCK;
    for (int j = tid; j < NBUCK; j += 256) h[j] = bhrow[j];
    __syncthreads();
    int j0 = 2 * tid, j1 = 2 * tid + 1;
    int a0 = (j0 < NBUCK) ? h[j0] : 0;
    int a1 = (j1 < NBUCK) ? h[j1] : 0;
    sc[tid] = a0 + a1;
    __syncthreads();
    for (int o = 1; o < 256; o <<= 1) {
        int v = (tid >= o) ? sc[tid - o] : 0;
        __syncthreads();
        sc[tid] += v;
        __syncthreads();
    }
    int base = sc[tid] - a0 - a1;
    if (j0 < NBUCK) { ls[j0] = base; gb[j0] = boff[j0] + bhprow[j0] - base; h[j0] = 0; }
    if (j1 < NBUCK) { ls[j1] = base + a0; gb[j1] = boff[j1] + bhprow[j1] - (base + a0); h[j1] = 0; }
    __syncthreads();
    int lo = b * CH, hi = min(lo + CH, NNZ_);
    for (int e = lo + tid; e < hi; e += 256) {
        int r = rows[e], c = cols[e];
        float v = vals[e];
        int bu = r >> BSH;
        int ru = atomicAdd(&h[bu], 1);
        int lp = ls[bu] + ru;
        buf[lp] = make_float2(__int_as_float(c | ((r & 511) << 20)), v);
        bid[lp] = (unsigned short)bu;
        int sI = N_U + c;
        int bi = sI >> BSH;
        int ri = atomicAdd(&h[bi], 1);
        lp = ls[bi] + ri;
        buf[lp] = make_float2(__int_as_float(r | ((sI & 511) << 20)), v);
        bid[lp] = (unsigned short)bi;
    }
    __syncthreads();
    int ntot = 2 * (hi - lo);
    for (int p = tid; p < ntot; p += 256) {
        int bu = bid[p];
        sv[gb[bu] + p] = buf[p];
    }
}

// phase 4: one block per bucket (512 segments): exact CSR placement.
// Final edge = idx(17b)<<15 | bf16(val)(15b, sign=0: vals >= 0) -- 4 bytes/edge.
__global__ __launch_bounds__(256) void place2_kernel(const float2* __restrict__ sv,
                                                     const int* __restrict__ boff,
                                                     const int* __restrict__ bcnt,
                                                     int* __restrict__ off, int* __restrict__ cnt,
                                                     unsigned* __restrict__ edge) {
    int b = blockIdx.x;
    int start = boff[b], n = bcnt[b];
    __shared__ int h[SPB], hs[SPB], hc[SPB];
    __shared__ int sc[256];
    int tid = threadIdx.x;
    h[tid] = 0; h[tid + 256] = 0;
    hc[tid] = 0; hc[tid + 256] = 0;
    __syncthreads();
    for (int i = start + tid; i < start + n; i += 256)
        atomicAdd(&h[(__float_as_int(sv[i].x) >> 20) & 511], 1);
    __syncthreads();
    int a0 = h[2 * tid], a1 = h[2 * tid + 1];
    sc[tid] = a0 + a1;
    __syncthreads();
    for (int o = 1; o < 256; o <<= 1) {
        int v = (tid >= o) ? sc[tid - o] : 0;
        __syncthreads();
        sc[tid] += v;
        __syncthreads();
    }
    int base = sc[tid] - a0 - a1;
    hs[2 * tid] = base;
    hs[2 * tid + 1] = base + a0;
    int seg0 = b * SPB + 2 * tid;
    if (seg0 < NSEG) { cnt[seg0] = a0; off[seg0] = start + base + a0; }  // END offsets
    if (seg0 + 1 < NSEG) { cnt[seg0 + 1] = a1; off[seg0 + 1] = start + base + a0 + a1; }
    __syncthreads();
    for (int i = start + tid; i < start + n; i += 256) {
        float2 p = sv[i];
        int packed = __float_as_int(p.x);
        int s = (packed >> 20) & 511;
        int r = atomicAdd(&hc[s], 1);
        unsigned vb = (unsigned)(unsigned short)f2bf(p.y);
        edge[start + hs[s] + r] = ((unsigned)(packed & 0xFFFFF) << 15) | (vb & 0x7FFFu);
    }
}

// wave-per-row CSR SpMM over 4-byte packed edges + bf16 gather table.
__global__ __launch_bounds__(256) void spmm_csr_kernel(
    const unsigned* __restrict__ edge, const int* __restrict__ off, const int* __restrict__ cnt,
    int base, const unsigned short* __restrict__ E16, float* __restrict__ out, float scale,
    int accum, int nrows) {
    int lane = threadIdx.x & 63;
    int row = (blockIdx.x * blockDim.x + threadIdx.x) >> 6;
    if (row >= nrows) return;
    int end = off[base + row];
    int n = cnt[base + row];
    int e = end - n;
    float acc = 0.f;
    while (e < end) {
        int m = min(64, end - e);
        unsigned pk = (lane < m) ? edge[e + lane] : 0u;
        int j = 0;
        for (; j + 8 <= m; j += 8) {
            unsigned p0 = (unsigned)__builtin_amdgcn_readlane((int)pk, j + 0);
            unsigned p1 = (unsigned)__builtin_amdgcn_readlane((int)pk, j + 1);
            unsigned p2 = (unsigned)__builtin_amdgcn_readlane((int)pk, j + 2);
            unsigned p3 = (unsigned)__builtin_amdgcn_readlane((int)pk, j + 3);
            unsigned p4 = (unsigned)__builtin_amdgcn_readlane((int)pk, j + 4);
            unsigned p5 = (unsigned)__builtin_amdgcn_readlane((int)pk, j + 5);
            unsigned p6 = (unsigned)__builtin_amdgcn_readlane((int)pk, j + 6);
            unsigned p7 = (unsigned)__builtin_amdgcn_readlane((int)pk, j + 7);
            float g0 = bfu(E16[(size_t)(p0 >> 15) * 64 + lane]);
            float g1 = bfu(E16[(size_t)(p1 >> 15) * 64 + lane]);
            float g2 = bfu(E16[(size_t)(p2 >> 15) * 64 + lane]);
            float g3 = bfu(E16[(size_t)(p3 >> 15) * 64 + lane]);
            float g4 = bfu(E16[(size_t)(p4 >> 15) * 64 + lane]);
            float g5 = bfu(E16[(size_t)(p5 >> 15) * 64 + lane]);
            float g6 = bfu(E16[(size_t)(p6 >> 15) * 64 + lane]);
            float g7 = bfu(E16[(size_t)(p7 >> 15) * 64 + lane]);
            acc = __builtin_fmaf(vdec(p0), g0, acc);
            acc = __builtin_fmaf(vdec(p1), g1, acc);
            acc = __builtin_fmaf(vdec(p2), g2, acc);
            acc = __builtin_fmaf(vdec(p3), g3, acc);
            acc = __builtin_fmaf(vdec(p4), g4, acc);
            acc = __builtin_fmaf(vdec(p5), g5, acc);
            acc = __builtin_fmaf(vdec(p6), g6, acc);
            acc = __builtin_fmaf(vdec(p7), g7, acc);
        }
        for (; j < m; j++) {
            unsigned p = (unsigned)__builtin_amdgcn_readlane((int)pk, j);
            acc = __builtin_fmaf(vdec(p), bfu(E16[(size_t)(p >> 15) * 64 + lane]), acc);
        }
        e += m;
    }
    size_t o = (size_t)row * 64 + lane;
    if (accum) out[o] += scale * acc;
    else out[o] = acc;
}

// rank reduction P[r][0:64] += sum_i W[r][i] * X[i][0:64]
__global__ __launch_bounds__(256) void rank_kernel(const float* __restrict__ X,
                                                   const float* __restrict__ W,
                                                   float* __restrict__ P, int n) {
    int lane = threadIdx.x & 63;
    int g = lane >> 4;
    int t = lane & 15;
    int wid = threadIdx.x >> 6;
    int wave = (blockIdx.x * blockDim.x + threadIdx.x) >> 6;
    int nw = (gridDim.x * blockDim.x) >> 6;
    int nq = n >> 2;
    float a[RANK][4];
#pragma unroll
    for (int r = 0; r < RANK; r++)
#pragma unroll
        for (int c = 0; c < 4; c++) a[r][c] = 0.f;
#pragma unroll 2
    for (int i4 = wave; i4 < nq; i4 += nw) {
        int row = i4 * 4 + g;
        float4 x = *(const float4*)(X + (size_t)row * 64 + t * 4);
#pragma unroll
        for (int r = 0; r < RANK; r++) {
            float w = W[(size_t)r * n + row];
            a[r][0] = __builtin_fmaf(w, x.x, a[r][0]);
            a[r][1] = __builtin_fmaf(w, x.y, a[r][1]);
            a[r][2] = __builtin_fmaf(w, x.z, a[r][2]);
            a[r][3] = __builtin_fmaf(w, x.w, a[r][3]);
        }
    }
#pragma unroll
    for (int r = 0; r < RANK; r++)
#pragma unroll
        for (int c = 0; c < 4; c++) {
            float v = a[r][c];
            v += __shfl_xor(v, 16);
            v += __shfl_xor(v, 32);
            a[r][c] = v;
        }
    __shared__ float ls[4][RANK * 64];
    if (g == 0) {
#pragma unroll
        for (int r = 0; r < RANK; r++)
#pragma unroll
            for (int c = 0; c < 4; c++) ls[wid][r * 64 + t * 4 + c] = a[r][c];
    }
    __syncthreads();
    int tid = threadIdx.x;
    if (tid < RANK * 64) {
        float s = ls[0][tid] + ls[1][tid] + ls[2][tid] + ls[3][tid];
        atomicAdd(&P[tid], s);
    }
}

__global__ void pre_out_kernel(const float4* __restrict__ a, const float4* __restrict__ b,
                               float4* __restrict__ o, int n) {
    int i = blockIdx.x * blockDim.x + threadIdx.x;
    if (i < n) {
        float4 x = a[i], y = b[i];
        const float s = 1.f / 3.f;
        o[i] = make_float4((x.x + y.x) * s, (x.y + y.y) * s, (x.z + y.z) * s, (x.w + y.w) * s);
    }
}

// vectorized: float4 in -> 4x bf16 out (all sizes are multiples of 4)
__global__ void conv_bf16_kernel(const float4* __restrict__ E, short4v* __restrict__ B, int n4,
                                 int npad4) {
    int i = blockIdx.x * blockDim.x + threadIdx.x;
    if (i >= npad4) return;
    short4v o = {0, 0, 0, 0};
    if (i < n4) {
        float4 x = E[i];
        o[0] = f2bf(x.x);
        o[1] = f2bf(x.y);
        o[2] = f2bf(x.z);
        o[3] = f2bf(x.w);
    }
    B[i] = o;
}

__global__ void gather_kernel(const int* __restrict__ ids, int m, const float* __restrict__ E0,
                              const float* __restrict__ PQ, const float* __restrict__ mulS,
                              const float* __restrict__ Eout, short* __restrict__ Gb,
                              float* __restrict__ acc, float coef) {
    int lane = threadIdx.x & 63;
    int wid = threadIdx.x >> 6;
    int k = (blockIdx.x * blockDim.x + threadIdx.x) >> 6;
    __shared__ float lacc[4];
    float t = 0.f;
    if (k < m) {
        int u = ids[k];
        float g = E0[u * 64 + lane];
#pragma unroll
        for (int r = 0; r < RANK; r++)
            g = __builtin_fmaf(mulS[u * RANK + r], PQ[r * 64 + lane], g);
        g *= (1.f / 3.f);
        Gb[k * 64 + lane] = f2bf(g);
        float d = g * Eout[u * 64 + lane];
#pragma unroll
        for (int off = 32; off; off >>= 1) d += __shfl_down(d, off);
        t = fminf(fmaxf(d * 5.f, -5.f), 5.f);
    }
    if (lane == 0) lacc[wid] = t;
    __syncthreads();
    if (threadIdx.x == 0)
        atomicAdd(acc, coef * (lacc[0] + lacc[1] + lacc[2] + lacc[3]));
}

// M-register-blocked neg-GEMM: each wave holds A for all 64 block rows (4 groups),
// sweeps CPW columns; per B-load-pair we issue 8 MFMAs + 16 exp-accumulates.
__global__ __launch_bounds__(256) void neg_mfma_kernel(const short* __restrict__ G16,
                                                       const short* __restrict__ E16,
                                                       float* __restrict__ part, int nchunk) {
    int lane = threadIdx.x & 63;
    int wave = threadIdx.x >> 6;
    int quad = lane >> 4;
    int rr = lane & 15;
    int rowbase = blockIdx.x * 64;
    short8 a0[4], a1[4];
#pragma unroll
    for (int g = 0; g < 4; g++) {
        const short8* ga = (const short8*)(G16 + (size_t)(rowbase + g * 16 + rr) * 64 + quad * 8);
        a0[g] = ga[0];
        a1[g] = ga[4];
    }
    int c0 = blockIdx.y * CPC + wave * CPW;
    float s[16];
#pragma unroll
    for (int i = 0; i < 16; i++) s[i] = 0.f;
    for (int ct = 0; ct < CPW; ct += 16) {
        const short8* eb = (const short8*)(E16 + (size_t)(c0 + ct + rr) * 64 + quad * 8);
        short8 b0 = eb[0];
        short8 b1 = eb[4];
#pragma unroll
        for (int g = 0; g < 4; g++) {
            floatx4 acc = {0.f, 0.f, 0.f, 0.f};
            acc = __builtin_amdgcn_mfma_f32_16x16x32_bf16(a0[g], b0, acc, 0, 0, 0);
            acc = __builtin_amdgcn_mfma_f32_16x16x32_bf16(a1[g], b1, acc, 0, 0, 0);
            s[g * 4 + 0] += __expf(acc[0] * 5.f);
            s[g * 4 + 1] += __expf(acc[1] * 5.f);
            s[g * 4 + 2] += __expf(acc[2] * 5.f);
            s[g * 4 + 3] += __expf(acc[3] * 5.f);
        }
    }
#pragma unroll
    for (int m = 8; m; m >>= 1) {
#pragma unroll
        for (int i = 0; i < 16; i++) s[i] += __shfl_xor(s[i], m);
    }
    if (rr == 0) {
        int col = blockIdx.y * 4 + wave;
#pragma unroll
        for (int g = 0; g < 4; g++) {
#pragma unroll
            for (int j = 0; j < 4; j++) {
                int row = rowbase + g * 16 + quad * 4 + j;
                part[(size_t)row * nchunk + col] = s[g * 4 + j];
            }
        }
    }
}

__global__ void combine_kernel(const float* __restrict__ part, int m, int nchunk, float pad,
                               float* __restrict__ acc, float coef) {
    int row = blockIdx.x * blockDim.x + threadIdx.x;
    int lane = threadIdx.x & 63, wid = threadIdx.x >> 6;
    float lse = 0.f;
    if (row < m) {
        float S = 0.f;
        for (int c = 0; c < nchunk; c++) S += part[(size_t)row * nchunk + c];
        lse = __logf(S - pad);
    }
#pragma unroll
    for (int off = 32; off; off >>= 1) lse += __shfl_down(lse, off);
    __shared__ float l2[4];
    if (lane == 0) l2[wid] = lse;
    __syncthreads();
    if (threadIdx.x == 0) atomicAdd(acc, coef * (l2[0] + l2[1] + l2[2] + l2[3]));
}

__global__ void cat_kernel(const float* __restrict__ img, const float* __restrict__ txt,
                           float* __restrict__ out, int nrows) {
    int lane = threadIdx.x & 63;
    int row = (blockIdx.x * blockDim.x + threadIdx.x) >> 6;
    if (row >= nrows) return;
    float a = img[row * 64 + lane], b = txt[row * 64 + lane];
    float sa = a * a, sb = b * b;
#pragma unroll
    for (int msk = 32; msk; msk >>= 1) { sa += __shfl_xor(sa, msk); sb += __shfl_xor(sb, msk); }
    float ia = 1.f / fmaxf(sqrtf(sa), 1e-12f);
    float ib = 1.f / fmaxf(sqrtf(sb), 1e-12f);
    out[row * 64 + lane] += 0.02f * (a * ia + b * ib);
}

__global__ void loss_write_kernel(const float* __restrict__ acc, float* __restrict__ out) {
    out[0] = acc[0];
}

extern "C" void kernel_launch(void* const* d_in, const int* in_sizes, int n_in,
                              void* d_out, int out_size, void* d_ws, size_t ws_size,
                              hipStream_t stream) {
    const float* user_emb = (const float*)d_in[0];
    const float* item_emb = (const float*)d_in[1];
    const float* user_pre = (const float*)d_in[2];
    const float* item_pre = (const float*)d_in[3];
    const float* img_i = (const float*)d_in[4];
    const float* txt_i = (const float*)d_in[5];
    const float* img_u = (const float*)d_in[6];
    const float* txt_u = (const float*)d_in[7];
    const int* rows = (const int*)d_in[8];
    const int* cols = (const int*)d_in[9];
    const float* vals = (const float*)d_in[10];
    const float* ut = (const float*)d_in[11];
    const float* vt = (const float*)d_in[12];
    const float* u_mul_s = (const float*)d_in[13];
    const float* v_mul_s = (const float*)d_in[14];
    const int* uids = (const int*)d_in[15];
    const int* iids = (const int*)d_in[16];

    float* ws = (float*)d_ws;
    float* zu1 = ws + ZU1;
    float* zi1 = ws + ZI1;
    unsigned* edge = (unsigned*)(ws + EDGE);
    float* P = ws + P_OFF;
    float* Q = ws + Q_OFF;
    float* acc = ws + ACC_OFF;
    int* cnt = (int*)(ws + CNT_OFF);
    int* off = (int*)(ws + OFF_OFF);
    int* bcnt = (int*)(ws + BCNT_OFF);
    int* boff = (int*)(ws + BOFF_OFF);
    int* bsum = (int*)(ws + BSUM_OFF);
    float* eu0 = ws + EU0;
    float* ei0 = ws + EI0;
    float* part_u = ws + PART_U;
    float* part_i = ws + PART_I;
    unsigned short* gtu = (unsigned short*)(ws + GTU);
    unsigned short* gti = (unsigned short*)(ws + GTI);
    int* bh = (int*)(ws + BH_OFF);
    int* bhp = (int*)(ws + BHP_OFF);
    float2* stage_sv = (float2*)(ws + STAGE_SV);
    short* ebu16 = (short*)(ws + EBU16);
    short* ebi16 = (short*)(ws + EBI16);
    short* gbu16 = (short*)(ws + GBU16);
    short* gbi16 = (short*)(ws + GBI16);

    float* out_u = (float*)d_out;
    float* out_i = out_u + (size_t)N_U * 64;
    float* out_loss = out_u + (size_t)(N_U + N_I) * 64;

    const int NB2 = (NBUCK + 255) / 256;  // 2 bucket-scan blocks

    // zero P,Q,acc only (cnt/off now written directly by place2)
    hipMemsetAsync(ws + P_OFF, 0, 704 * sizeof(float), stream);

    // ---- atomic-free CSR/CSC build ----
    bhist_kernel<<<NPB, 256, 0, stream>>>(rows, cols, bh);
    col_scan_kernel<<<NB2, 256, 0, stream>>>(bh, bhp, bcnt);
    scan1_kernel<<<NB2, 256, 0, stream>>>(bcnt, bsum, NBUCK);
    scan2_kernel<<<1, 1024, 0, stream>>>(bsum, NB2);
    scan3_kernel<<<NB2, 256, 0, stream>>>(bcnt, bsum, boff, NBUCK);
    bucket_place_kernel<<<NPB, 256, 0, stream>>>(rows, cols, vals, boff, bh, bhp, stage_sv);
    place2_kernel<<<NBUCK, 256, 0, stream>>>(stage_sv, boff, bcnt, off, cnt, edge);

    // E0 = pre + emb
    ew_add_kernel<<<6250, 256, 0, stream>>>((const float4*)user_emb, (const float4*)user_pre,
                                            (float4*)eu0, 1600000);
    ew_add_kernel<<<3125, 256, 0, stream>>>((const float4*)item_emb, (const float4*)item_pre,
                                            (float4*)ei0, 800000);
    // bf16 gather tables for layer-1 spmm
    conv_bf16_kernel<<<3125, 256, 0, stream>>>((const float4*)ei0, (short4v*)gti, 800000, 800000);
    conv_bf16_kernel<<<6250, 256, 0, stream>>>((const float4*)eu0, (short4v*)gtu, 1600000,
                                               1600000);
    // layer-1 rank reductions
    rank_kernel<<<1024, 256, 0, stream>>>(ei0, vt, P, N_I);
    rank_kernel<<<1024, 256, 0, stream>>>(eu0, ut, Q, N_U);
    // layer-1 SpMM (bf16 gather)
    spmm_csr_kernel<<<N_U / 4, 256, 0, stream>>>(edge, off, cnt, 0, gti, zu1, 1.f, 0, N_U);
    spmm_csr_kernel<<<N_I / 4, 256, 0, stream>>>(edge, off, cnt, N_U, gtu, zi1, 1.f, 0, N_I);
    // bf16 gather tables for layer-2 spmm (overwrite)
    conv_bf16_kernel<<<3125, 256, 0, stream>>>((const float4*)zi1, (short4v*)gti, 800000, 800000);
    conv_bf16_kernel<<<6250, 256, 0, stream>>>((const float4*)zu1, (short4v*)gtu, 1600000,
                                               1600000);
    // layer-2 rank reductions
    rank_kernel<<<1024, 256, 0, stream>>>(zi1, vt, P, N_I);
    rank_kernel<<<1024, 256, 0, stream>>>(zu1, ut, Q, N_U);
    // out = (E0 + Z1)/3, then layer-2 SpMM accumulates Z2/3 into out
    pre_out_kernel<<<6250, 256, 0, stream>>>((const float4*)eu0, (const float4*)zu1,
                                             (float4*)out_u, 1600000);
    pre_out_kernel<<<3125, 256, 0, stream>>>((const float4*)ei0, (const float4*)zi1,
                                             (float4*)out_i, 800000);
    spmm_csr_kernel<<<N_U / 4, 256, 0, stream>>>(edge, off, cnt, 0, gti, out_u, 1.f / 3.f, 1,
                                                 N_U);
    spmm_csr_kernel<<<N_I / 4, 256, 0, stream>>>(edge, off, cnt, N_U, gtu, out_i, 1.f / 3.f, 1,
                                                 N_I);
    // bf16 copies of E (overlay in dead zu1 region; zero-padded tail rows)
    conv_bf16_kernel<<<6272, 256, 0, stream>>>((const float4*)out_u, (short4v*)ebu16, 1600000,
                                               NPAD_U * 16);
    conv_bf16_kernel<<<3136, 256, 0, stream>>>((const float4*)out_i, (short4v*)ebi16, 800000,
                                               NPAD_I * 16);
    // sampled G rows (bf16) + pos term (fp32)
    gather_kernel<<<M_U / 4, 256, 0, stream>>>(uids, M_U, eu0, P, u_mul_s, out_u, gbu16, acc,
                                               -4.f / M_U);
    gather_kernel<<<M_I / 4, 256, 0, stream>>>(iids, M_I, ei0, Q, v_mul_s, out_i, gbi16, acc,
                                               -4.f / M_I);
    // neg term: MFMA exp-sum (4 chunk-columns per blockIdx.y: one per wave)
    dim3 gu(M_U / 64, NCH_U);
    neg_mfma_kernel<<<gu, 256, 0, stream>>>(gbu16, ebu16, part_u, NCH_U * 4);
    dim3 gi(M_I / 64, NCH_I);
    neg_mfma_kernel<<<gi, 256, 0, stream>>>(gbi16, ebi16, part_i, NCH_I * 4);
    combine_kernel<<<(M_U + 255) / 256, 256, 0, stream>>>(part_u, M_U, NCH_U * 4,
                                                          (float)(NPAD_U - N_U), acc, 4.f / M_U);
    combine_kernel<<<(M_I + 255) / 256, 256, 0, stream>>>(part_i, M_I, NCH_I * 4,
                                                          (float)(NPAD_I - N_I), acc, 4.f / M_I);
    // cat-rate terms (after loss consumed E from d_out)
    cat_kernel<<<(N_U * 64 + 255) / 256, 256, 0, stream>>>(img_u, txt_u, out_u, N_U);
    cat_kernel<<<(N_I * 64 + 255) / 256, 256, 0, stream>>>(img_i, txt_i, out_i, N_I);
    loss_write_kernel<<<1, 1, 0, stream>>>(acc, out_loss);
}